// Round 1
// baseline (792.928 us; speedup 1.0000x reference)
//
#include <hip/hip_runtime.h>
#include <hip/hip_bf16.h>

// GCN 2-layer forward, two graphs, shared weights.
// CSR build: two-level counting sort (unchanged).
// GEMM (rewritten): register-direct A fragments (no LDS round-trip for A, no
//   per-chunk barriers), W staged once/block in XOR-swizzled LDS, persistent
//   grid-stride waves. Split-bf16 3-term MFMA (fp32-equivalent accuracy).
// SpMM: one wave/row, 4 edges per gather instruction; fused selu / l2norm.

#define RPB 512
#define EPB 4096
#define MAXB 8192

typedef __attribute__((ext_vector_type(8))) short short8;
typedef __attribute__((ext_vector_type(4))) short short4v;
typedef __attribute__((ext_vector_type(4))) float f32x4;

__device__ __forceinline__ float selu_f(float x) {
    const float scale = 1.0507009873554805f;
    const float alpha = 1.6732632423543772f;
    return x > 0.0f ? scale * x : scale * alpha * (__expf(x) - 1.0f);
}

__device__ __forceinline__ short f2bf(float x) {   // RNE truncate fp32->bf16
    unsigned u = __float_as_uint(x);
    u += 0x7FFF + ((u >> 16) & 1);
    return (short)(u >> 16);
}
__device__ __forceinline__ float bf2f(short h) {
    return __uint_as_float(((unsigned)(unsigned short)h) << 16);
}

// ---------------- scan (generic) ----------------
__global__ void scan_a(const int* __restrict__ counts, int* __restrict__ offs,
                       int* __restrict__ partials, int N) {
    __shared__ int sh[256];
    int tid = threadIdx.x;
    int base = blockIdx.x * 1024 + tid * 4;
    int4 c = make_int4(0, 0, 0, 0);
    if (base + 3 < N) {
        c = *(const int4*)(counts + base);
    } else {
        if (base + 0 < N) c.x = counts[base + 0];
        if (base + 1 < N) c.y = counts[base + 1];
        if (base + 2 < N) c.z = counts[base + 2];
        if (base + 3 < N) c.w = counts[base + 3];
    }
    int tsum = c.x + c.y + c.z + c.w;
    sh[tid] = tsum;
    __syncthreads();
    int val = tsum;
    for (int d = 1; d < 256; d <<= 1) {
        int t = (tid >= d) ? sh[tid - d] : 0;
        __syncthreads();
        val += t;
        sh[tid] = val;
        __syncthreads();
    }
    int excl = val - tsum;
    int4 o;
    o.x = excl; o.y = o.x + c.x; o.z = o.y + c.y; o.w = o.z + c.z;
    if (base + 3 < N) {
        *(int4*)(offs + base) = o;
    } else {
        if (base + 0 < N) offs[base + 0] = o.x;
        if (base + 1 < N) offs[base + 1] = o.y;
        if (base + 2 < N) offs[base + 2] = o.z;
        if (base + 3 < N) offs[base + 3] = o.w;
    }
    if (tid == 255) partials[blockIdx.x] = val;
}

__global__ void scan_b(int* __restrict__ partials, int nb) {
    __shared__ int sh[128];
    int tid = threadIdx.x;
    int v = (tid < nb) ? partials[tid] : 0;
    sh[tid] = v;
    __syncthreads();
    int val = v;
    for (int d = 1; d < 128; d <<= 1) {
        int t = (tid >= d) ? sh[tid - d] : 0;
        __syncthreads();
        val += t;
        sh[tid] = val;
        __syncthreads();
    }
    if (tid < nb) partials[tid] = val - v;
}

__global__ void scan_c(int* __restrict__ offs, const int* __restrict__ partials,
                       int N, int E) {
    int tid = threadIdx.x;
    int base = blockIdx.x * 1024 + tid * 4;
    int add = partials[blockIdx.x];
    if (base + 3 < N) {
        int4 o = *(int4*)(offs + base);
        o.x += add; o.y += add; o.z += add; o.w += add;
        *(int4*)(offs + base) = o;
    } else {
        for (int t = 0; t < 4; t++)
            if (base + t < N) offs[base + t] += add;
    }
    if (blockIdx.x == 0 && tid == 0) offs[N] = E;
}

// ---------------- pass A1: coarse histogram ----------------
__global__ __launch_bounds__(256) void bucket_hist(const int* __restrict__ rows,
                                                   int* __restrict__ cntT,
                                                   int E, int nbA, int NB) {
    __shared__ int cnt[256];
    int tid = threadIdx.x;
    cnt[tid] = 0;
    __syncthreads();
    int e0 = blockIdx.x * EPB;
#pragma unroll
    for (int k = 0; k < EPB / 256; k++) {
        int e = e0 + k * 256 + tid;
        if (e < E) atomicAdd(&cnt[rows[e] >> 9], 1);
    }
    __syncthreads();
    if (tid < NB) cntT[tid * nbA + blockIdx.x] = cnt[tid];
}

// ---------------- pass A2: block-local counting sort ----------------
__global__ __launch_bounds__(256) void coarse_scatter(const int* __restrict__ rows,
                                                      const int* __restrict__ cols,
                                                      const float* __restrict__ vals,
                                                      const int* __restrict__ csOffs,
                                                      int2* __restrict__ ecvA,
                                                      int E, int nbA, int NB) {
    __shared__ int cnt[256];
    __shared__ int loc[256];
    __shared__ int gof[256];
    __shared__ int dstBase[EPB];
    __shared__ int2 eLDS[EPB];
    int tid = threadIdx.x, blk = blockIdx.x;
    int e0 = blk * EPB;
    cnt[tid] = 0;
    __syncthreads();
#pragma unroll
    for (int k = 0; k < EPB / 256; k++) {
        int e = e0 + k * 256 + tid;
        if (e < E) atomicAdd(&cnt[rows[e] >> 9], 1);
    }
    __syncthreads();
    int my = cnt[tid];
    loc[tid] = my;
    __syncthreads();
    int val = my;
    for (int d = 1; d < 256; d <<= 1) {
        int t = (tid >= d) ? loc[tid - d] : 0;
        __syncthreads();
        val += t;
        loc[tid] = val;
        __syncthreads();
    }
    int excl = val - my;
    loc[tid] = excl;
    cnt[tid] = excl;
    gof[tid] = (tid < NB) ? csOffs[tid * nbA + blk] : 0;
    __syncthreads();
#pragma unroll
    for (int k = 0; k < EPB / 256; k++) {
        int e = e0 + k * 256 + tid;
        if (e < E) {
            int r = rows[e];
            int b = r >> 9;
            int p = atomicAdd(&cnt[b], 1);
            eLDS[p] = make_int2(((r & (RPB - 1)) << 17) | cols[e],
                                __float_as_int(vals[e]));
            dstBase[p] = gof[b] - loc[b];
        }
    }
    __syncthreads();
    int nE = min(EPB, E - e0);
    for (int j = tid; j < nE; j += 256)
        ecvA[dstBase[j] + j] = eLDS[j];
}

// ---------------- pass B: per-bucket fine sort ----------------
__global__ __launch_bounds__(256) void fine_sort(const int* __restrict__ csOffs,
                                                 const int2* __restrict__ ecvA,
                                                 int2* __restrict__ ecv,
                                                 int* __restrict__ offs,
                                                 int nbA, int N, int E) {
    __shared__ int rcnt[RPB], roff[RPB], rcur[RPB];
    __shared__ int sh[256];
    __shared__ int2 eLDS[MAXB];
    int b = blockIdx.x, tid = threadIdx.x;
    int bs = csOffs[b * nbA];
    int be = csOffs[(b + 1) * nbA];
    int cntE = be - bs;
    if (cntE > MAXB) cntE = MAXB;
    rcnt[tid] = 0;
    rcnt[tid + 256] = 0;
    __syncthreads();
    for (int j = tid; j < cntE; j += 256)
        atomicAdd(&rcnt[ecvA[bs + j].x >> 17], 1);
    __syncthreads();
    int a0 = rcnt[2 * tid], a1 = rcnt[2 * tid + 1];
    int ps = a0 + a1;
    sh[tid] = ps;
    __syncthreads();
    int val = ps;
    for (int d = 1; d < 256; d <<= 1) {
        int t = (tid >= d) ? sh[tid - d] : 0;
        __syncthreads();
        val += t;
        sh[tid] = val;
        __syncthreads();
    }
    int exclPair = val - ps;
    roff[2 * tid] = exclPair;
    roff[2 * tid + 1] = exclPair + a0;
    rcur[2 * tid] = exclPair;
    rcur[2 * tid + 1] = exclPair + a0;
    __syncthreads();
    int row0 = b * RPB;
    for (int t2 = tid; t2 < RPB; t2 += 256) {
        int row = row0 + t2;
        if (row <= N) offs[row] = bs + roff[t2];
    }
    if (b == 0 && tid == 0) offs[N] = E;
    for (int j = tid; j < cntE; j += 256) {
        int2 p = ecvA[bs + j];
        int pos = atomicAdd(&rcur[p.x >> 17], 1);
        if (pos < MAXB) eLDS[pos] = make_int2(p.x & 0x1FFFF, p.y);
    }
    __syncthreads();
    for (int j = tid; j < cntE; j += 256)
        ecv[bs + j] = eLDS[j];
}

// ---------------- weight prep: fp32 [K][64] -> bf16 hi/lo transposed [64][K] --
__global__ void prep_w(const float* __restrict__ W, short* __restrict__ th,
                       short* __restrict__ tl, int K) {
    int idx = blockIdx.x * 256 + threadIdx.x;
    if (idx < K * 64) {
        int k = idx >> 6, n = idx & 63;
        float x = W[idx];
        short h = f2bf(x);
        short l = f2bf(x - bf2f(h));
        th[n * K + k] = h;
        tl[n * K + k] = l;
    }
}

// ---------------- MFMA GEMM: C[M,64] = A[M,K] @ W[K,64] ----------------
// Register-direct A: the 16x16x32 A-fragment is 8 contiguous k per lane
// (row = lane&15, k-offset = (lane>>4)*8) -> 2 float4 global loads per lane
// per k-slice, converted to split-bf16 in registers. No LDS for A, no barriers
// in the main loop. W (pre-split hi/lo, [n][K]) staged once per block into
// LDS with short-index XOR swizzle k ^ ((n&7)<<3): breaks the 512B-row-stride
// same-bank pattern so ds_read_b128 B-fragment reads are conflict-free.
// 512 threads = 8 waves; each wave owns 16-row tiles via grid-stride.
template<int K>
__global__ __launch_bounds__(512, 4) void gemm_reg(const float* __restrict__ A,
                                                   const short* __restrict__ Wth,
                                                   const short* __restrict__ Wtl,
                                                   float* __restrict__ C, int M) {
    constexpr int KS = K / 32;            // k-slices per tile: 8 (K=256) / 2 (K=64)
    __shared__ short Wh[64 * K];          // K=256: 32KB each -> 64KB total
    __shared__ short Wl[64 * K];
    int tid = threadIdx.x;
    {   // stage W once: thread t -> row n = t>>3, 8 threads/row, 16B chunks
        int n = tid >> 3;
        int xm = (n & 7) << 3;
#pragma unroll
        for (int i = 0; i < K / 64; i++) {
            int k0 = ((tid & 7) + 8 * i) * 8;
            int src = n * K + k0;
            int dst = n * K + (k0 ^ xm);
            *(short8*)(&Wh[dst]) = *(const short8*)(Wth + src);
            *(short8*)(&Wl[dst]) = *(const short8*)(Wtl + src);
        }
    }
    __syncthreads();
    int wave = tid >> 6, lane = tid & 63;
    int m = lane & 15, q = lane >> 4;
    int nT = (M + 15) >> 4;
    int gw = gridDim.x * 8;
    for (int t = blockIdx.x * 8 + wave; t < nT; t += gw) {
        int arow = t * 16 + m;
        if (arow >= M) arow = M - 1;      // safe dup; OOB rows never stored
        const float* a = A + (size_t)arow * K + q * 8;
        short8 ah[KS], al[KS];
#pragma unroll
        for (int ks = 0; ks < KS; ks++) {
            float4 f0 = *(const float4*)(a + ks * 32);
            float4 f1 = *(const float4*)(a + ks * 32 + 4);
            float f[8] = {f0.x, f0.y, f0.z, f0.w, f1.x, f1.y, f1.z, f1.w};
            short8 h, l;
#pragma unroll
            for (int j = 0; j < 8; j++) {
                short hh = f2bf(f[j]);
                h[j] = hh;
                l[j] = f2bf(f[j] - bf2f(hh));
            }
            ah[ks] = h; al[ks] = l;
        }
        f32x4 acc[4] = {{0.f, 0.f, 0.f, 0.f}, {0.f, 0.f, 0.f, 0.f},
                        {0.f, 0.f, 0.f, 0.f}, {0.f, 0.f, 0.f, 0.f}};
#pragma unroll
        for (int nt = 0; nt < 4; nt++) {
            int n = nt * 16 + m;
            int base = n * K;
            int xm = (n & 7) << 3;
#pragma unroll
            for (int ks = 0; ks < KS; ks++) {
                int off = base + ((ks * 32 + q * 8) ^ xm);
                short8 bh = *(const short8*)(&Wh[off]);
                short8 bl = *(const short8*)(&Wl[off]);
                acc[nt] = __builtin_amdgcn_mfma_f32_16x16x32_bf16(ah[ks], bh, acc[nt], 0, 0, 0);
                acc[nt] = __builtin_amdgcn_mfma_f32_16x16x32_bf16(al[ks], bh, acc[nt], 0, 0, 0);
                acc[nt] = __builtin_amdgcn_mfma_f32_16x16x32_bf16(ah[ks], bl, acc[nt], 0, 0, 0);
            }
        }
        // epilogue: C/D layout col=lane&15, row=q*4+reg
#pragma unroll
        for (int nt = 0; nt < 4; nt++) {
#pragma unroll
            for (int r = 0; r < 4; r++) {
                int grow = t * 16 + q * 4 + r;
                if (grow < M) C[(size_t)grow * 64 + nt * 16 + m] = acc[nt][r];
            }
        }
    }
}

// ---------------- SpMM: one wave/row, 4 edges per gather instruction ---------
__device__ __forceinline__ void spmm_row4(const int* __restrict__ offs,
                                          const int2* __restrict__ ecv,
                                          const float* __restrict__ H,
                                          int row, int g, int f4,
                                          float& ax, float& ay, float& az, float& aw) {
    int s = offs[row], e = offs[row + 1];
    s = __builtin_amdgcn_readfirstlane(s);
    e = __builtin_amdgcn_readfirstlane(e);
    ax = ay = az = aw = 0.f;
    for (int i = s; i < e; i += 8) {
        int i0 = i + g, i1 = i + 4 + g;
        int2 p0 = ecv[i0 < e ? i0 : (e - 1)];
        int2 p1 = ecv[i1 < e ? i1 : (e - 1)];
        float v0 = (i0 < e) ? __int_as_float(p0.y) : 0.f;
        float v1 = (i1 < e) ? __int_as_float(p1.y) : 0.f;
        float4 h0 = *(const float4*)(H + (size_t)p0.x * 64 + f4);
        float4 h1 = *(const float4*)(H + (size_t)p1.x * 64 + f4);
        ax = fmaf(v0, h0.x, ax); ay = fmaf(v0, h0.y, ay);
        az = fmaf(v0, h0.z, az); aw = fmaf(v0, h0.w, aw);
        ax = fmaf(v1, h1.x, ax); ay = fmaf(v1, h1.y, ay);
        az = fmaf(v1, h1.z, az); aw = fmaf(v1, h1.w, aw);
    }
#pragma unroll
    for (int d = 16; d <= 32; d <<= 1) {
        ax += __shfl_xor(ax, d, 64);
        ay += __shfl_xor(ay, d, 64);
        az += __shfl_xor(az, d, 64);
        aw += __shfl_xor(aw, d, 64);
    }
}

__global__ __launch_bounds__(256) void spmm_selu(const int* __restrict__ offs,
                                                 const int2* __restrict__ ecv,
                                                 const float* __restrict__ H,
                                                 const float* __restrict__ bias,
                                                 float* __restrict__ out, int N) {
    int row = blockIdx.x * 4 + (threadIdx.x >> 6);
    if (row >= N) return;
    int lane = threadIdx.x & 63;
    int g = lane >> 4, f4 = (lane & 15) * 4;
    float ax, ay, az, aw;
    spmm_row4(offs, ecv, H, row, g, f4, ax, ay, az, aw);
    float4 b = *(const float4*)(bias + f4);
    if (g == 0) {
        float4 o;
        o.x = selu_f(ax + b.x);
        o.y = selu_f(ay + b.y);
        o.z = selu_f(az + b.z);
        o.w = selu_f(aw + b.w);
        *(float4*)(out + (size_t)row * 64 + f4) = o;
    }
}

__global__ __launch_bounds__(256) void spmm_norm(const int* __restrict__ offs,
                                                 const int2* __restrict__ ecv,
                                                 const float* __restrict__ H,
                                                 const float* __restrict__ bias,
                                                 float* __restrict__ out, int N) {
    int row = blockIdx.x * 4 + (threadIdx.x >> 6);
    if (row >= N) return;
    int lane = threadIdx.x & 63;
    int g = lane >> 4, f4 = (lane & 15) * 4;
    float ax, ay, az, aw;
    spmm_row4(offs, ecv, H, row, g, f4, ax, ay, az, aw);
    float4 b = *(const float4*)(bias + f4);
    float zx = ax + b.x, zy = ay + b.y, zz = az + b.z, zw = aw + b.w;
    float s2 = zx * zx + zy * zy + zz * zz + zw * zw;
#pragma unroll
    for (int d = 1; d <= 8; d <<= 1) s2 += __shfl_xor(s2, d, 64);
    float inv = 1.0f / fmaxf(sqrtf(s2), 1e-12f);
    if (g == 0) {
        float4 o;
        o.x = zx * inv; o.y = zy * inv; o.z = zz * inv; o.w = zw * inv;
        *(float4*)(out + (size_t)row * 64 + f4) = o;
    }
}

extern "C" void kernel_launch(void* const* d_in, const int* in_sizes, int n_in,
                              void* d_out, int out_size, void* d_ws, size_t ws_size,
                              hipStream_t stream) {
    const int IN_DIM = 256, HID = 64;
    const int N = in_sizes[0] / IN_DIM;   // 100000
    const int E = in_sizes[2];            // 1200000

    const float* X[2]    = {(const float*)d_in[0], (const float*)d_in[1]};
    const int*   rows[2] = {(const int*)d_in[2], (const int*)d_in[5]};
    const int*   cols[2] = {(const int*)d_in[3], (const int*)d_in[6]};
    const float* vals[2] = {(const float*)d_in[4], (const float*)d_in[7]};
    const float* W1 = (const float*)d_in[8];
    const float* b1 = (const float*)d_in[9];
    const float* W2 = (const float*)d_in[10];
    const float* b2 = (const float*)d_in[11];
    float* out = (float*)d_out;

    const int NB  = (N + RPB - 1) / RPB;      // 196
    const int nbA = (E + EPB - 1) / EPB;      // 293
    const int M   = NB * nbA;
    const int nbScanM = (M + 1023) / 1024;    // 57
    const int nbRow  = (N + 3) / 4;           // 25000
    const int nT = (N + 15) / 16;             // 6250 row-tiles
    const int nbG1 = 512;                     // 2 blocks/CU (64KB LDS), grid-stride
    const int nbG2 = (nT + 7) / 8;            // 782: ~1 tile/wave

    auto align16 = [](char* p) { return (char*)(((uintptr_t)p + 15) & ~(uintptr_t)15); };
    char* w = (char*)d_ws;
    float* bufA   = (float*)w; w += (size_t)N * HID * sizeof(float);
    float* bufB   = (float*)w; w += (size_t)N * HID * sizeof(float);
    w = align16(w);
    int2*  ecv    = (int2*)w;  w += (size_t)E * sizeof(int2);
    w = align16(w);
    int*   cntT   = (int*)w;   w += (size_t)M * sizeof(int);
    w = align16(w);
    int*   csOffs = (int*)w;   w += (size_t)(M + 1) * sizeof(int);
    w = align16(w);
    int*   offs   = (int*)w;   w += (size_t)(N + 1) * sizeof(int);
    w = align16(w);
    int*   partials = (int*)w; w += 1024;
    w = align16(w);
    short* w1th = (short*)w;   w += (size_t)64 * IN_DIM * sizeof(short);
    short* w1tl = (short*)w;   w += (size_t)64 * IN_DIM * sizeof(short);
    short* w2th = (short*)w;   w += (size_t)64 * HID * sizeof(short);
    short* w2tl = (short*)w;   w += (size_t)64 * HID * sizeof(short);
    int2*  ecvA = (int2*)bufA;   // alias: CSR temp, dead before gemm writes bufA

    // weight prep (tiny, once per call)
    prep_w<<<(IN_DIM * 64 + 255) / 256, 256, 0, stream>>>(W1, w1th, w1tl, IN_DIM);
    prep_w<<<(HID * 64 + 255) / 256, 256, 0, stream>>>(W2, w2th, w2tl, HID);

    for (int g = 0; g < 2; g++) {
        // CSR build
        bucket_hist<<<nbA, 256, 0, stream>>>(rows[g], cntT, E, nbA, NB);
        scan_a<<<nbScanM, 256, 0, stream>>>(cntT, csOffs, partials, M);
        scan_b<<<1, 128, 0, stream>>>(partials, nbScanM);
        scan_c<<<nbScanM, 256, 0, stream>>>(csOffs, partials, M, E);
        coarse_scatter<<<nbA, 256, 0, stream>>>(rows[g], cols[g], vals[g], csOffs,
                                                ecvA, E, nbA, NB);
        fine_sort<<<NB, 256, 0, stream>>>(csOffs, ecvA, ecv, offs, nbA, N, E);
        // layer 1
        gemm_reg<256><<<nbG1, 512, 0, stream>>>(X[g], w1th, w1tl, bufA, N);
        spmm_selu<<<nbRow, 256, 0, stream>>>(offs, ecv, bufA, b1, bufB, N);
        // layer 2
        gemm_reg<64><<<nbG2, 512, 0, stream>>>(bufB, w2th, w2tl, bufA, N);
        spmm_norm<<<nbRow, 256, 0, stream>>>(offs, ecv, bufA, b2,
                                             out + (size_t)g * N * HID, N);
    }
}

// Round 2
// 599.005 us; speedup vs baseline: 1.3237x; 1.3237x over previous
//
#include <hip/hip_runtime.h>
#include <hip/hip_bf16.h>

// GCN 2-layer forward, two graphs, shared weights.
// CSR build: two-level counting sort (unchanged from 616us baseline).
// GEMM: MFMA 16x16x32 bf16 split-bf16 3-term, 64x64 tile, LDS staging for A+W
//   (block-coalesced loads -> bounded L2 working set -> near-ideal HBM traffic;
//   R1's register-direct variant caused 8x write amplification, reverted).
//   NEW: register-level A-prefetch across K-chunks (reg loads are NOT drained
//   by __syncthreads, unlike global_load_lds) -> HBM latency hides under
//   convert+MFMA of the previous chunk.
// SpMM: one wave/row, 4 edges per gather instruction; fused selu / l2norm.

#define RPB 512
#define EPB 4096
#define MAXB 8192

typedef __attribute__((ext_vector_type(8))) short short8;
typedef __attribute__((ext_vector_type(4))) short short4v;
typedef __attribute__((ext_vector_type(4))) float f32x4;

__device__ __forceinline__ float selu_f(float x) {
    const float scale = 1.0507009873554805f;
    const float alpha = 1.6732632423543772f;
    return x > 0.0f ? scale * x : scale * alpha * (__expf(x) - 1.0f);
}

__device__ __forceinline__ short f2bf(float x) {   // RNE truncate fp32->bf16
    unsigned u = __float_as_uint(x);
    u += 0x7FFF + ((u >> 16) & 1);
    return (short)(u >> 16);
}
__device__ __forceinline__ float bf2f(short h) {
    return __uint_as_float(((unsigned)(unsigned short)h) << 16);
}

// ---------------- scan (generic) ----------------
__global__ void scan_a(const int* __restrict__ counts, int* __restrict__ offs,
                       int* __restrict__ partials, int N) {
    __shared__ int sh[256];
    int tid = threadIdx.x;
    int base = blockIdx.x * 1024 + tid * 4;
    int4 c = make_int4(0, 0, 0, 0);
    if (base + 3 < N) {
        c = *(const int4*)(counts + base);
    } else {
        if (base + 0 < N) c.x = counts[base + 0];
        if (base + 1 < N) c.y = counts[base + 1];
        if (base + 2 < N) c.z = counts[base + 2];
        if (base + 3 < N) c.w = counts[base + 3];
    }
    int tsum = c.x + c.y + c.z + c.w;
    sh[tid] = tsum;
    __syncthreads();
    int val = tsum;
    for (int d = 1; d < 256; d <<= 1) {
        int t = (tid >= d) ? sh[tid - d] : 0;
        __syncthreads();
        val += t;
        sh[tid] = val;
        __syncthreads();
    }
    int excl = val - tsum;
    int4 o;
    o.x = excl; o.y = o.x + c.x; o.z = o.y + c.y; o.w = o.z + c.z;
    if (base + 3 < N) {
        *(int4*)(offs + base) = o;
    } else {
        if (base + 0 < N) offs[base + 0] = o.x;
        if (base + 1 < N) offs[base + 1] = o.y;
        if (base + 2 < N) offs[base + 2] = o.z;
        if (base + 3 < N) offs[base + 3] = o.w;
    }
    if (tid == 255) partials[blockIdx.x] = val;
}

__global__ void scan_b(int* __restrict__ partials, int nb) {
    __shared__ int sh[128];
    int tid = threadIdx.x;
    int v = (tid < nb) ? partials[tid] : 0;
    sh[tid] = v;
    __syncthreads();
    int val = v;
    for (int d = 1; d < 128; d <<= 1) {
        int t = (tid >= d) ? sh[tid - d] : 0;
        __syncthreads();
        val += t;
        sh[tid] = val;
        __syncthreads();
    }
    if (tid < nb) partials[tid] = val - v;
}

__global__ void scan_c(int* __restrict__ offs, const int* __restrict__ partials,
                       int N, int E) {
    int tid = threadIdx.x;
    int base = blockIdx.x * 1024 + tid * 4;
    int add = partials[blockIdx.x];
    if (base + 3 < N) {
        int4 o = *(int4*)(offs + base);
        o.x += add; o.y += add; o.z += add; o.w += add;
        *(int4*)(offs + base) = o;
    } else {
        for (int t = 0; t < 4; t++)
            if (base + t < N) offs[base + t] += add;
    }
    if (blockIdx.x == 0 && tid == 0) offs[N] = E;
}

// ---------------- pass A1: coarse histogram ----------------
__global__ __launch_bounds__(256) void bucket_hist(const int* __restrict__ rows,
                                                   int* __restrict__ cntT,
                                                   int E, int nbA, int NB) {
    __shared__ int cnt[256];
    int tid = threadIdx.x;
    cnt[tid] = 0;
    __syncthreads();
    int e0 = blockIdx.x * EPB;
#pragma unroll
    for (int k = 0; k < EPB / 256; k++) {
        int e = e0 + k * 256 + tid;
        if (e < E) atomicAdd(&cnt[rows[e] >> 9], 1);
    }
    __syncthreads();
    if (tid < NB) cntT[tid * nbA + blockIdx.x] = cnt[tid];
}

// ---------------- pass A2: block-local counting sort ----------------
__global__ __launch_bounds__(256) void coarse_scatter(const int* __restrict__ rows,
                                                      const int* __restrict__ cols,
                                                      const float* __restrict__ vals,
                                                      const int* __restrict__ csOffs,
                                                      int2* __restrict__ ecvA,
                                                      int E, int nbA, int NB) {
    __shared__ int cnt[256];
    __shared__ int loc[256];
    __shared__ int gof[256];
    __shared__ int dstBase[EPB];
    __shared__ int2 eLDS[EPB];
    int tid = threadIdx.x, blk = blockIdx.x;
    int e0 = blk * EPB;
    cnt[tid] = 0;
    __syncthreads();
#pragma unroll
    for (int k = 0; k < EPB / 256; k++) {
        int e = e0 + k * 256 + tid;
        if (e < E) atomicAdd(&cnt[rows[e] >> 9], 1);
    }
    __syncthreads();
    int my = cnt[tid];
    loc[tid] = my;
    __syncthreads();
    int val = my;
    for (int d = 1; d < 256; d <<= 1) {
        int t = (tid >= d) ? loc[tid - d] : 0;
        __syncthreads();
        val += t;
        loc[tid] = val;
        __syncthreads();
    }
    int excl = val - my;
    loc[tid] = excl;
    cnt[tid] = excl;
    gof[tid] = (tid < NB) ? csOffs[tid * nbA + blk] : 0;
    __syncthreads();
#pragma unroll
    for (int k = 0; k < EPB / 256; k++) {
        int e = e0 + k * 256 + tid;
        if (e < E) {
            int r = rows[e];
            int b = r >> 9;
            int p = atomicAdd(&cnt[b], 1);
            eLDS[p] = make_int2(((r & (RPB - 1)) << 17) | cols[e],
                                __float_as_int(vals[e]));
            dstBase[p] = gof[b] - loc[b];
        }
    }
    __syncthreads();
    int nE = min(EPB, E - e0);
    for (int j = tid; j < nE; j += 256)
        ecvA[dstBase[j] + j] = eLDS[j];
}

// ---------------- pass B: per-bucket fine sort ----------------
__global__ __launch_bounds__(256) void fine_sort(const int* __restrict__ csOffs,
                                                 const int2* __restrict__ ecvA,
                                                 int2* __restrict__ ecv,
                                                 int* __restrict__ offs,
                                                 int nbA, int N, int E) {
    __shared__ int rcnt[RPB], roff[RPB], rcur[RPB];
    __shared__ int sh[256];
    __shared__ int2 eLDS[MAXB];
    int b = blockIdx.x, tid = threadIdx.x;
    int bs = csOffs[b * nbA];
    int be = csOffs[(b + 1) * nbA];
    int cntE = be - bs;
    if (cntE > MAXB) cntE = MAXB;
    rcnt[tid] = 0;
    rcnt[tid + 256] = 0;
    __syncthreads();
    for (int j = tid; j < cntE; j += 256)
        atomicAdd(&rcnt[ecvA[bs + j].x >> 17], 1);
    __syncthreads();
    int a0 = rcnt[2 * tid], a1 = rcnt[2 * tid + 1];
    int ps = a0 + a1;
    sh[tid] = ps;
    __syncthreads();
    int val = ps;
    for (int d = 1; d < 256; d <<= 1) {
        int t = (tid >= d) ? sh[tid - d] : 0;
        __syncthreads();
        val += t;
        sh[tid] = val;
        __syncthreads();
    }
    int exclPair = val - ps;
    roff[2 * tid] = exclPair;
    roff[2 * tid + 1] = exclPair + a0;
    rcur[2 * tid] = exclPair;
    rcur[2 * tid + 1] = exclPair + a0;
    __syncthreads();
    int row0 = b * RPB;
    for (int t2 = tid; t2 < RPB; t2 += 256) {
        int row = row0 + t2;
        if (row <= N) offs[row] = bs + roff[t2];
    }
    if (b == 0 && tid == 0) offs[N] = E;
    for (int j = tid; j < cntE; j += 256) {
        int2 p = ecvA[bs + j];
        int pos = atomicAdd(&rcur[p.x >> 17], 1);
        if (pos < MAXB) eLDS[pos] = make_int2(p.x & 0x1FFFF, p.y);
    }
    __syncthreads();
    for (int j = tid; j < cntE; j += 256)
        ecv[bs + j] = eLDS[j];
}

// ---------------- weight prep: fp32 [K][64] -> bf16 hi/lo transposed [64][K] --
__global__ void prep_w(const float* __restrict__ W, short* __restrict__ th,
                       short* __restrict__ tl, int K) {
    int idx = blockIdx.x * 256 + threadIdx.x;
    if (idx < K * 64) {
        int k = idx >> 6, n = idx & 63;
        float x = W[idx];
        short h = f2bf(x);
        short l = f2bf(x - bf2f(h));
        th[n * K + k] = h;
        tl[n * K + k] = l;
    }
}

// ---------------- MFMA GEMM: C[M,64] = A[M,K] @ W[K,64] ----------------
// Block: 256 thr = 4 waves; tile 64 rows x 64 cols; wave w -> rows 16w..16w+15,
// 4 N-tiles of 16. K-chunks of 64. Register prefetch: chunk c+1's A loads are
// issued before chunk c's convert/MFMA; W loads issue at stage-phase top so
// their L2 latency hides under the A convert VALU work.
template<int K>
__global__ __launch_bounds__(256) void gemm_mfma(const float* __restrict__ A,
                                                 const short* __restrict__ Wth,
                                                 const short* __restrict__ Wtl,
                                                 float* __restrict__ C, int M) {
    constexpr int NC = K / 64;
    __shared__ short Ah[64 * 72], Al[64 * 72];   // [row][k], stride 72 (pad 8)
    __shared__ short Wh[64 * 72], Wl[64 * 72];   // [n][k],   stride 72
    int tid = threadIdx.x;
    int wave = tid >> 6, lane = tid & 63;
    int m = lane & 15, q = lane >> 4;
    int row0 = blockIdx.x * 64;
    int ai = tid >> 4;            // row within quarter: 0..15
    int aj = (tid & 15) * 4;      // col: 0,4,..,60
    f32x4 acc[4] = {{0.f, 0.f, 0.f, 0.f}, {0.f, 0.f, 0.f, 0.f},
                    {0.f, 0.f, 0.f, 0.f}, {0.f, 0.f, 0.f, 0.f}};

    // prologue: A chunk 0 -> regs
    float4 ga[4];
#pragma unroll
    for (int v = 0; v < 4; v++) {
        int gr = row0 + v * 16 + ai;
        ga[v] = make_float4(0.f, 0.f, 0.f, 0.f);
        if (gr < M) ga[v] = *(const float4*)(A + (size_t)gr * K + aj);
    }

#pragma unroll
    for (int c = 0; c < NC; c++) {
        // W chunk c -> regs (issued first; L2-resident, hides under convert)
        short4v whv[4], wlv[4];
#pragma unroll
        for (int v = 0; v < 4; v++) {
            size_t wo = (size_t)(v * 16 + ai) * K + c * 64 + aj;
            whv[v] = *(const short4v*)(Wth + wo);
            wlv[v] = *(const short4v*)(Wtl + wo);
        }
        // prefetch next A chunk -> regs (hides HBM latency under this chunk)
        float4 gan[4];
        if (c + 1 < NC) {
#pragma unroll
            for (int v = 0; v < 4; v++) {
                int gr = row0 + v * 16 + ai;
                gan[v] = make_float4(0.f, 0.f, 0.f, 0.f);
                if (gr < M)
                    gan[v] = *(const float4*)(A + (size_t)gr * K + (c + 1) * 64 + aj);
            }
        }
        // convert current A (regs) -> split-bf16 LDS
#pragma unroll
        for (int v = 0; v < 4; v++) {
            int r = v * 16 + ai;
            float f[4] = {ga[v].x, ga[v].y, ga[v].z, ga[v].w};
            short4v h, l;
#pragma unroll
            for (int j = 0; j < 4; j++) {
                short hh = f2bf(f[j]);
                h[j] = hh;
                l[j] = f2bf(f[j] - bf2f(hh));
            }
            *(short4v*)(&Ah[r * 72 + aj]) = h;
            *(short4v*)(&Al[r * 72 + aj]) = l;
        }
        // W regs -> LDS
#pragma unroll
        for (int v = 0; v < 4; v++) {
            int n = v * 16 + ai;
            *(short4v*)(&Wh[n * 72 + aj]) = whv[v];
            *(short4v*)(&Wl[n * 72 + aj]) = wlv[v];
        }
        __syncthreads();
        int ar = (16 * wave + m) * 72;
        short8 ah0 = *(const short8*)(&Ah[ar + q * 8]);
        short8 ah1 = *(const short8*)(&Ah[ar + 32 + q * 8]);
        short8 al0 = *(const short8*)(&Al[ar + q * 8]);
        short8 al1 = *(const short8*)(&Al[ar + 32 + q * 8]);
#pragma unroll
        for (int nt = 0; nt < 4; nt++) {
            int nb = (nt * 16 + m) * 72;
            short8 bh0 = *(const short8*)(&Wh[nb + q * 8]);
            short8 bh1 = *(const short8*)(&Wh[nb + 32 + q * 8]);
            short8 bl0 = *(const short8*)(&Wl[nb + q * 8]);
            short8 bl1 = *(const short8*)(&Wl[nb + 32 + q * 8]);
            acc[nt] = __builtin_amdgcn_mfma_f32_16x16x32_bf16(ah0, bh0, acc[nt], 0, 0, 0);
            acc[nt] = __builtin_amdgcn_mfma_f32_16x16x32_bf16(al0, bh0, acc[nt], 0, 0, 0);
            acc[nt] = __builtin_amdgcn_mfma_f32_16x16x32_bf16(ah0, bl0, acc[nt], 0, 0, 0);
            acc[nt] = __builtin_amdgcn_mfma_f32_16x16x32_bf16(ah1, bh1, acc[nt], 0, 0, 0);
            acc[nt] = __builtin_amdgcn_mfma_f32_16x16x32_bf16(al1, bh1, acc[nt], 0, 0, 0);
            acc[nt] = __builtin_amdgcn_mfma_f32_16x16x32_bf16(ah1, bl1, acc[nt], 0, 0, 0);
        }
        if (c + 1 < NC) {
            __syncthreads();       // protect LDS before next chunk's overwrite
#pragma unroll
            for (int v = 0; v < 4; v++) ga[v] = gan[v];
        }
    }
    // epilogue: C/D layout col=lane&15, row=q*4+reg
#pragma unroll
    for (int nt = 0; nt < 4; nt++) {
#pragma unroll
        for (int r = 0; r < 4; r++) {
            int grow = row0 + 16 * wave + q * 4 + r;
            if (grow < M) C[(size_t)grow * 64 + nt * 16 + m] = acc[nt][r];
        }
    }
}

// ---------------- SpMM: one wave/row, 4 edges per gather instruction ---------
__device__ __forceinline__ void spmm_row4(const int* __restrict__ offs,
                                          const int2* __restrict__ ecv,
                                          const float* __restrict__ H,
                                          int row, int g, int f4,
                                          float& ax, float& ay, float& az, float& aw) {
    int s = offs[row], e = offs[row + 1];
    s = __builtin_amdgcn_readfirstlane(s);
    e = __builtin_amdgcn_readfirstlane(e);
    ax = ay = az = aw = 0.f;
    for (int i = s; i < e; i += 8) {
        int i0 = i + g, i1 = i + 4 + g;
        int2 p0 = ecv[i0 < e ? i0 : (e - 1)];
        int2 p1 = ecv[i1 < e ? i1 : (e - 1)];
        float v0 = (i0 < e) ? __int_as_float(p0.y) : 0.f;
        float v1 = (i1 < e) ? __int_as_float(p1.y) : 0.f;
        float4 h0 = *(const float4*)(H + (size_t)p0.x * 64 + f4);
        float4 h1 = *(const float4*)(H + (size_t)p1.x * 64 + f4);
        ax = fmaf(v0, h0.x, ax); ay = fmaf(v0, h0.y, ay);
        az = fmaf(v0, h0.z, az); aw = fmaf(v0, h0.w, aw);
        ax = fmaf(v1, h1.x, ax); ay = fmaf(v1, h1.y, ay);
        az = fmaf(v1, h1.z, az); aw = fmaf(v1, h1.w, aw);
    }
#pragma unroll
    for (int d = 16; d <= 32; d <<= 1) {
        ax += __shfl_xor(ax, d, 64);
        ay += __shfl_xor(ay, d, 64);
        az += __shfl_xor(az, d, 64);
        aw += __shfl_xor(aw, d, 64);
    }
}

__global__ __launch_bounds__(256) void spmm_selu(const int* __restrict__ offs,
                                                 const int2* __restrict__ ecv,
                                                 const float* __restrict__ H,
                                                 const float* __restrict__ bias,
                                                 float* __restrict__ out, int N) {
    int row = blockIdx.x * 4 + (threadIdx.x >> 6);
    if (row >= N) return;
    int lane = threadIdx.x & 63;
    int g = lane >> 4, f4 = (lane & 15) * 4;
    float ax, ay, az, aw;
    spmm_row4(offs, ecv, H, row, g, f4, ax, ay, az, aw);
    float4 b = *(const float4*)(bias + f4);
    if (g == 0) {
        float4 o;
        o.x = selu_f(ax + b.x);
        o.y = selu_f(ay + b.y);
        o.z = selu_f(az + b.z);
        o.w = selu_f(aw + b.w);
        *(float4*)(out + (size_t)row * 64 + f4) = o;
    }
}

__global__ __launch_bounds__(256) void spmm_norm(const int* __restrict__ offs,
                                                 const int2* __restrict__ ecv,
                                                 const float* __restrict__ H,
                                                 const float* __restrict__ bias,
                                                 float* __restrict__ out, int N) {
    int row = blockIdx.x * 4 + (threadIdx.x >> 6);
    if (row >= N) return;
    int lane = threadIdx.x & 63;
    int g = lane >> 4, f4 = (lane & 15) * 4;
    float ax, ay, az, aw;
    spmm_row4(offs, ecv, H, row, g, f4, ax, ay, az, aw);
    float4 b = *(const float4*)(bias + f4);
    float zx = ax + b.x, zy = ay + b.y, zz = az + b.z, zw = aw + b.w;
    float s2 = zx * zx + zy * zy + zz * zz + zw * zw;
#pragma unroll
    for (int d = 1; d <= 8; d <<= 1) s2 += __shfl_xor(s2, d, 64);
    float inv = 1.0f / fmaxf(sqrtf(s2), 1e-12f);
    if (g == 0) {
        float4 o;
        o.x = zx * inv; o.y = zy * inv; o.z = zz * inv; o.w = zw * inv;
        *(float4*)(out + (size_t)row * 64 + f4) = o;
    }
}

extern "C" void kernel_launch(void* const* d_in, const int* in_sizes, int n_in,
                              void* d_out, int out_size, void* d_ws, size_t ws_size,
                              hipStream_t stream) {
    const int IN_DIM = 256, HID = 64;
    const int N = in_sizes[0] / IN_DIM;   // 100000
    const int E = in_sizes[2];            // 1200000

    const float* X[2]    = {(const float*)d_in[0], (const float*)d_in[1]};
    const int*   rows[2] = {(const int*)d_in[2], (const int*)d_in[5]};
    const int*   cols[2] = {(const int*)d_in[3], (const int*)d_in[6]};
    const float* vals[2] = {(const float*)d_in[4], (const float*)d_in[7]};
    const float* W1 = (const float*)d_in[8];
    const float* b1 = (const float*)d_in[9];
    const float* W2 = (const float*)d_in[10];
    const float* b2 = (const float*)d_in[11];
    float* out = (float*)d_out;

    const int NB  = (N + RPB - 1) / RPB;      // 196
    const int nbA = (E + EPB - 1) / EPB;      // 293
    const int M   = NB * nbA;
    const int nbScanM = (M + 1023) / 1024;    // 57
    const int nbGemm = (N + 63) / 64;         // 1563
    const int nbRow  = (N + 3) / 4;           // 25000

    auto align16 = [](char* p) { return (char*)(((uintptr_t)p + 15) & ~(uintptr_t)15); };
    char* w = (char*)d_ws;
    float* bufA   = (float*)w; w += (size_t)N * HID * sizeof(float);
    float* bufB   = (float*)w; w += (size_t)N * HID * sizeof(float);
    w = align16(w);
    int2*  ecv    = (int2*)w;  w += (size_t)E * sizeof(int2);
    w = align16(w);
    int*   cntT   = (int*)w;   w += (size_t)M * sizeof(int);
    w = align16(w);
    int*   csOffs = (int*)w;   w += (size_t)(M + 1) * sizeof(int);
    w = align16(w);
    int*   offs   = (int*)w;   w += (size_t)(N + 1) * sizeof(int);
    w = align16(w);
    int*   partials = (int*)w; w += 1024;
    w = align16(w);
    short* w1th = (short*)w;   w += (size_t)64 * IN_DIM * sizeof(short);
    short* w1tl = (short*)w;   w += (size_t)64 * IN_DIM * sizeof(short);
    short* w2th = (short*)w;   w += (size_t)64 * HID * sizeof(short);
    short* w2tl = (short*)w;   w += (size_t)64 * HID * sizeof(short);
    int2*  ecvA = (int2*)bufA;   // alias: CSR temp, dead before gemm writes bufA

    // weight prep (tiny, once per call)
    prep_w<<<(IN_DIM * 64 + 255) / 256, 256, 0, stream>>>(W1, w1th, w1tl, IN_DIM);
    prep_w<<<(HID * 64 + 255) / 256, 256, 0, stream>>>(W2, w2th, w2tl, HID);

    for (int g = 0; g < 2; g++) {
        // CSR build
        bucket_hist<<<nbA, 256, 0, stream>>>(rows[g], cntT, E, nbA, NB);
        scan_a<<<nbScanM, 256, 0, stream>>>(cntT, csOffs, partials, M);
        scan_b<<<1, 128, 0, stream>>>(partials, nbScanM);
        scan_c<<<nbScanM, 256, 0, stream>>>(csOffs, partials, M, E);
        coarse_scatter<<<nbA, 256, 0, stream>>>(rows[g], cols[g], vals[g], csOffs,
                                                ecvA, E, nbA, NB);
        fine_sort<<<NB, 256, 0, stream>>>(csOffs, ecvA, ecv, offs, nbA, N, E);
        // layer 1
        gemm_mfma<256><<<nbGemm, 256, 0, stream>>>(X[g], w1th, w1tl, bufA, N);
        spmm_selu<<<nbRow, 256, 0, stream>>>(offs, ecv, bufA, b1, bufB, N);
        // layer 2
        gemm_mfma<64><<<nbGemm, 256, 0, stream>>>(bufB, w2th, w2tl, bufA, N);
        spmm_norm<<<nbRow, 256, 0, stream>>>(offs, ecv, bufA, b2,
                                             out + (size_t)g * N * HID, N);
    }
}

// Round 3
// 537.552 us; speedup vs baseline: 1.4751x; 1.1143x over previous
//
#include <hip/hip_runtime.h>
#include <hip/hip_bf16.h>

// GCN 2-layer forward, two graphs, shared weights.
// R3: both graphs batched into every dispatch (gridDim.y=2) -> 22 dispatches
//     become 12; under-subscribed CSR kernels (fine_sort 196 blocks, scans 57,
//     scan_b 1!) double their grids. Per-kernel inner code identical to the
//     verified R2 version (pointer-offset plumbing only).
// GEMM: MFMA 16x16x32 bf16 split-bf16 3-term, 64x64 tile, LDS staging,
//     register-level A-prefetch across K-chunks.
// SpMM: one wave/row, 4 edges per gather instruction; fused selu / l2norm.

#define RPB 512
#define EPB 4096
#define MAXB 8192

typedef __attribute__((ext_vector_type(8))) short short8;
typedef __attribute__((ext_vector_type(4))) short short4v;
typedef __attribute__((ext_vector_type(4))) float f32x4;

__device__ __forceinline__ float selu_f(float x) {
    const float scale = 1.0507009873554805f;
    const float alpha = 1.6732632423543772f;
    return x > 0.0f ? scale * x : scale * alpha * (__expf(x) - 1.0f);
}

__device__ __forceinline__ short f2bf(float x) {   // RNE truncate fp32->bf16
    unsigned u = __float_as_uint(x);
    u += 0x7FFF + ((u >> 16) & 1);
    return (short)(u >> 16);
}
__device__ __forceinline__ float bf2f(short h) {
    return __uint_as_float(((unsigned)(unsigned short)h) << 16);
}

// ---------------- scan (batched over graphs via blockIdx.y) ----------------
__global__ void scan_a(const int* __restrict__ countsB, int* __restrict__ offsB,
                       int* __restrict__ partialsB, int N) {
    const int* counts = countsB + (size_t)blockIdx.y * N;
    int* offs = offsB + (size_t)blockIdx.y * (N + 1);
    int* partials = partialsB + (size_t)blockIdx.y * 512;
    __shared__ int sh[256];
    int tid = threadIdx.x;
    int base = blockIdx.x * 1024 + tid * 4;
    int4 c = make_int4(0, 0, 0, 0);
    if (base + 3 < N) {
        c = *(const int4*)(counts + base);
    } else {
        if (base + 0 < N) c.x = counts[base + 0];
        if (base + 1 < N) c.y = counts[base + 1];
        if (base + 2 < N) c.z = counts[base + 2];
        if (base + 3 < N) c.w = counts[base + 3];
    }
    int tsum = c.x + c.y + c.z + c.w;
    sh[tid] = tsum;
    __syncthreads();
    int val = tsum;
    for (int d = 1; d < 256; d <<= 1) {
        int t = (tid >= d) ? sh[tid - d] : 0;
        __syncthreads();
        val += t;
        sh[tid] = val;
        __syncthreads();
    }
    int excl = val - tsum;
    int4 o;
    o.x = excl; o.y = o.x + c.x; o.z = o.y + c.y; o.w = o.z + c.z;
    if (base + 3 < N) {
        *(int4*)(offs + base) = o;
    } else {
        if (base + 0 < N) offs[base + 0] = o.x;
        if (base + 1 < N) offs[base + 1] = o.y;
        if (base + 2 < N) offs[base + 2] = o.z;
        if (base + 3 < N) offs[base + 3] = o.w;
    }
    if (tid == 255) partials[blockIdx.x] = val;
}

__global__ void scan_b(int* __restrict__ partialsB, int nb) {
    int* partials = partialsB + (size_t)blockIdx.y * 512;
    __shared__ int sh[128];
    int tid = threadIdx.x;
    int v = (tid < nb) ? partials[tid] : 0;
    sh[tid] = v;
    __syncthreads();
    int val = v;
    for (int d = 1; d < 128; d <<= 1) {
        int t = (tid >= d) ? sh[tid - d] : 0;
        __syncthreads();
        val += t;
        sh[tid] = val;
        __syncthreads();
    }
    if (tid < nb) partials[tid] = val - v;
}

__global__ void scan_c(int* __restrict__ offsB, const int* __restrict__ partialsB,
                       int N, int E) {
    int* offs = offsB + (size_t)blockIdx.y * (N + 1);
    const int* partials = partialsB + (size_t)blockIdx.y * 512;
    int tid = threadIdx.x;
    int base = blockIdx.x * 1024 + tid * 4;
    int add = partials[blockIdx.x];
    if (base + 3 < N) {
        int4 o = *(int4*)(offs + base);
        o.x += add; o.y += add; o.z += add; o.w += add;
        *(int4*)(offs + base) = o;
    } else {
        for (int t = 0; t < 4; t++)
            if (base + t < N) offs[base + t] += add;
    }
    if (blockIdx.x == 0 && tid == 0) offs[N] = E;
}

// ---------------- pass A1: coarse histogram (batched) ----------------
__global__ __launch_bounds__(256) void bucket_hist(const int* __restrict__ r0,
                                                   const int* __restrict__ r1,
                                                   int* __restrict__ cntTB,
                                                   int E, int nbA, int NB, int M) {
    const int* rows = blockIdx.y ? r1 : r0;
    int* cntT = cntTB + (size_t)blockIdx.y * M;
    __shared__ int cnt[256];
    int tid = threadIdx.x;
    cnt[tid] = 0;
    __syncthreads();
    int e0 = blockIdx.x * EPB;
#pragma unroll
    for (int k = 0; k < EPB / 256; k++) {
        int e = e0 + k * 256 + tid;
        if (e < E) atomicAdd(&cnt[rows[e] >> 9], 1);
    }
    __syncthreads();
    if (tid < NB) cntT[tid * nbA + blockIdx.x] = cnt[tid];
}

// ---------------- pass A2: block-local counting sort (batched) --------------
__global__ __launch_bounds__(256) void coarse_scatter(const int* __restrict__ r0,
                                                      const int* __restrict__ r1,
                                                      const int* __restrict__ c0,
                                                      const int* __restrict__ c1,
                                                      const float* __restrict__ v0,
                                                      const float* __restrict__ v1,
                                                      const int* __restrict__ csOffsB,
                                                      int2* __restrict__ ecvAB,
                                                      int E, int nbA, int NB, int M) {
    const int* rows = blockIdx.y ? r1 : r0;
    const int* cols = blockIdx.y ? c1 : c0;
    const float* vals = blockIdx.y ? v1 : v0;
    const int* csOffs = csOffsB + (size_t)blockIdx.y * (M + 1);
    int2* ecvA = ecvAB + (size_t)blockIdx.y * E;
    __shared__ int cnt[256];
    __shared__ int loc[256];
    __shared__ int gof[256];
    __shared__ int dstBase[EPB];
    __shared__ int2 eLDS[EPB];
    int tid = threadIdx.x, blk = blockIdx.x;
    int e0 = blk * EPB;
    cnt[tid] = 0;
    __syncthreads();
#pragma unroll
    for (int k = 0; k < EPB / 256; k++) {
        int e = e0 + k * 256 + tid;
        if (e < E) atomicAdd(&cnt[rows[e] >> 9], 1);
    }
    __syncthreads();
    int my = cnt[tid];
    loc[tid] = my;
    __syncthreads();
    int val = my;
    for (int d = 1; d < 256; d <<= 1) {
        int t = (tid >= d) ? loc[tid - d] : 0;
        __syncthreads();
        val += t;
        loc[tid] = val;
        __syncthreads();
    }
    int excl = val - my;
    loc[tid] = excl;
    cnt[tid] = excl;
    gof[tid] = (tid < NB) ? csOffs[tid * nbA + blk] : 0;
    __syncthreads();
#pragma unroll
    for (int k = 0; k < EPB / 256; k++) {
        int e = e0 + k * 256 + tid;
        if (e < E) {
            int r = rows[e];
            int b = r >> 9;
            int p = atomicAdd(&cnt[b], 1);
            eLDS[p] = make_int2(((r & (RPB - 1)) << 17) | cols[e],
                                __float_as_int(vals[e]));
            dstBase[p] = gof[b] - loc[b];
        }
    }
    __syncthreads();
    int nE = min(EPB, E - e0);
    for (int j = tid; j < nE; j += 256)
        ecvA[dstBase[j] + j] = eLDS[j];
}

// ---------------- pass B: per-bucket fine sort (batched) ----------------
__global__ __launch_bounds__(256) void fine_sort(const int* __restrict__ csOffsB,
                                                 const int2* __restrict__ ecvAB,
                                                 int2* __restrict__ ecvB,
                                                 int* __restrict__ offsB,
                                                 int nbA, int N, int E, int M) {
    const int* csOffs = csOffsB + (size_t)blockIdx.y * (M + 1);
    const int2* ecvA = ecvAB + (size_t)blockIdx.y * E;
    int2* ecv = ecvB + (size_t)blockIdx.y * E;
    int* offs = offsB + (size_t)blockIdx.y * (N + 1);
    __shared__ int rcnt[RPB], roff[RPB], rcur[RPB];
    __shared__ int sh[256];
    __shared__ int2 eLDS[MAXB];
    int b = blockIdx.x, tid = threadIdx.x;
    int bs = csOffs[b * nbA];
    int be = csOffs[(b + 1) * nbA];
    int cntE = be - bs;
    if (cntE > MAXB) cntE = MAXB;
    rcnt[tid] = 0;
    rcnt[tid + 256] = 0;
    __syncthreads();
    for (int j = tid; j < cntE; j += 256)
        atomicAdd(&rcnt[ecvA[bs + j].x >> 17], 1);
    __syncthreads();
    int a0 = rcnt[2 * tid], a1 = rcnt[2 * tid + 1];
    int ps = a0 + a1;
    sh[tid] = ps;
    __syncthreads();
    int val = ps;
    for (int d = 1; d < 256; d <<= 1) {
        int t = (tid >= d) ? sh[tid - d] : 0;
        __syncthreads();
        val += t;
        sh[tid] = val;
        __syncthreads();
    }
    int exclPair = val - ps;
    roff[2 * tid] = exclPair;
    roff[2 * tid + 1] = exclPair + a0;
    rcur[2 * tid] = exclPair;
    rcur[2 * tid + 1] = exclPair + a0;
    __syncthreads();
    int row0 = b * RPB;
    for (int t2 = tid; t2 < RPB; t2 += 256) {
        int row = row0 + t2;
        if (row <= N) offs[row] = bs + roff[t2];
    }
    if (b == 0 && tid == 0) offs[N] = E;
    for (int j = tid; j < cntE; j += 256) {
        int2 p = ecvA[bs + j];
        int pos = atomicAdd(&rcur[p.x >> 17], 1);
        if (pos < MAXB) eLDS[pos] = make_int2(p.x & 0x1FFFF, p.y);
    }
    __syncthreads();
    for (int j = tid; j < cntE; j += 256)
        ecv[bs + j] = eLDS[j];
}

// ---------------- weight prep: both weights in one dispatch ----------------
__global__ void prep_w2(const float* __restrict__ W1, short* __restrict__ th1,
                        short* __restrict__ tl1,
                        const float* __restrict__ W2, short* __restrict__ th2,
                        short* __restrict__ tl2) {
    int idx = blockIdx.x * 256 + threadIdx.x;
    const int n1 = 256 * 64;
    if (idx < n1) {
        int k = idx >> 6, n = idx & 63;
        float x = W1[idx];
        short h = f2bf(x);
        short l = f2bf(x - bf2f(h));
        th1[n * 256 + k] = h;
        tl1[n * 256 + k] = l;
    } else if (idx - n1 < 64 * 64) {
        int i2 = idx - n1;
        int k = i2 >> 6, n = i2 & 63;
        float x = W2[i2];
        short h = f2bf(x);
        short l = f2bf(x - bf2f(h));
        th2[n * 64 + k] = h;
        tl2[n * 64 + k] = l;
    }
}

// ---------------- MFMA GEMM: C[M,64] = A[M,K] @ W[K,64], batched ------------
// Block: 256 thr = 4 waves; tile 64 rows x 64 cols. K-chunks of 64 with
// register A-prefetch (reg loads not drained by __syncthreads).
template<int K>
__global__ __launch_bounds__(256) void gemm_mfma(const float* __restrict__ A0,
                                                 const float* __restrict__ A1,
                                                 const short* __restrict__ Wth,
                                                 const short* __restrict__ Wtl,
                                                 float* __restrict__ C0,
                                                 float* __restrict__ C1, int M) {
    constexpr int NC = K / 64;
    const float* A = blockIdx.y ? A1 : A0;
    float* C = blockIdx.y ? C1 : C0;
    __shared__ short Ah[64 * 72], Al[64 * 72];   // [row][k], stride 72 (pad 8)
    __shared__ short Wh[64 * 72], Wl[64 * 72];   // [n][k],   stride 72
    int tid = threadIdx.x;
    int wave = tid >> 6, lane = tid & 63;
    int m = lane & 15, q = lane >> 4;
    int row0 = blockIdx.x * 64;
    int ai = tid >> 4;            // row within quarter: 0..15
    int aj = (tid & 15) * 4;      // col: 0,4,..,60
    f32x4 acc[4] = {{0.f, 0.f, 0.f, 0.f}, {0.f, 0.f, 0.f, 0.f},
                    {0.f, 0.f, 0.f, 0.f}, {0.f, 0.f, 0.f, 0.f}};

    // prologue: A chunk 0 -> regs
    float4 ga[4];
#pragma unroll
    for (int v = 0; v < 4; v++) {
        int gr = row0 + v * 16 + ai;
        ga[v] = make_float4(0.f, 0.f, 0.f, 0.f);
        if (gr < M) ga[v] = *(const float4*)(A + (size_t)gr * K + aj);
    }

#pragma unroll
    for (int c = 0; c < NC; c++) {
        // W chunk c -> regs (issued first; L2-resident, hides under convert)
        short4v whv[4], wlv[4];
#pragma unroll
        for (int v = 0; v < 4; v++) {
            size_t wo = (size_t)(v * 16 + ai) * K + c * 64 + aj;
            whv[v] = *(const short4v*)(Wth + wo);
            wlv[v] = *(const short4v*)(Wtl + wo);
        }
        // prefetch next A chunk -> regs (hides HBM latency under this chunk)
        float4 gan[4];
        if (c + 1 < NC) {
#pragma unroll
            for (int v = 0; v < 4; v++) {
                int gr = row0 + v * 16 + ai;
                gan[v] = make_float4(0.f, 0.f, 0.f, 0.f);
                if (gr < M)
                    gan[v] = *(const float4*)(A + (size_t)gr * K + (c + 1) * 64 + aj);
            }
        }
        // convert current A (regs) -> split-bf16 LDS
#pragma unroll
        for (int v = 0; v < 4; v++) {
            int r = v * 16 + ai;
            float f[4] = {ga[v].x, ga[v].y, ga[v].z, ga[v].w};
            short4v h, l;
#pragma unroll
            for (int j = 0; j < 4; j++) {
                short hh = f2bf(f[j]);
                h[j] = hh;
                l[j] = f2bf(f[j] - bf2f(hh));
            }
            *(short4v*)(&Ah[r * 72 + aj]) = h;
            *(short4v*)(&Al[r * 72 + aj]) = l;
        }
        // W regs -> LDS
#pragma unroll
        for (int v = 0; v < 4; v++) {
            int n = v * 16 + ai;
            *(short4v*)(&Wh[n * 72 + aj]) = whv[v];
            *(short4v*)(&Wl[n * 72 + aj]) = wlv[v];
        }
        __syncthreads();
        int ar = (16 * wave + m) * 72;
        short8 ah0 = *(const short8*)(&Ah[ar + q * 8]);
        short8 ah1 = *(const short8*)(&Ah[ar + 32 + q * 8]);
        short8 al0 = *(const short8*)(&Al[ar + q * 8]);
        short8 al1 = *(const short8*)(&Al[ar + 32 + q * 8]);
#pragma unroll
        for (int nt = 0; nt < 4; nt++) {
            int nb = (nt * 16 + m) * 72;
            short8 bh0 = *(const short8*)(&Wh[nb + q * 8]);
            short8 bh1 = *(const short8*)(&Wh[nb + 32 + q * 8]);
            short8 bl0 = *(const short8*)(&Wl[nb + q * 8]);
            short8 bl1 = *(const short8*)(&Wl[nb + 32 + q * 8]);
            acc[nt] = __builtin_amdgcn_mfma_f32_16x16x32_bf16(ah0, bh0, acc[nt], 0, 0, 0);
            acc[nt] = __builtin_amdgcn_mfma_f32_16x16x32_bf16(al0, bh0, acc[nt], 0, 0, 0);
            acc[nt] = __builtin_amdgcn_mfma_f32_16x16x32_bf16(ah0, bl0, acc[nt], 0, 0, 0);
            acc[nt] = __builtin_amdgcn_mfma_f32_16x16x32_bf16(ah1, bh1, acc[nt], 0, 0, 0);
            acc[nt] = __builtin_amdgcn_mfma_f32_16x16x32_bf16(al1, bh1, acc[nt], 0, 0, 0);
            acc[nt] = __builtin_amdgcn_mfma_f32_16x16x32_bf16(ah1, bl1, acc[nt], 0, 0, 0);
        }
        if (c + 1 < NC) {
            __syncthreads();       // protect LDS before next chunk's overwrite
#pragma unroll
            for (int v = 0; v < 4; v++) ga[v] = gan[v];
        }
    }
    // epilogue: C/D layout col=lane&15, row=q*4+reg
#pragma unroll
    for (int nt = 0; nt < 4; nt++) {
#pragma unroll
        for (int r = 0; r < 4; r++) {
            int grow = row0 + 16 * wave + q * 4 + r;
            if (grow < M) C[(size_t)grow * 64 + nt * 16 + m] = acc[nt][r];
        }
    }
}

// ---------------- SpMM: one wave/row, 4 edges per gather instruction ---------
__device__ __forceinline__ void spmm_row4(const int* __restrict__ offs,
                                          const int2* __restrict__ ecv,
                                          const float* __restrict__ H,
                                          int row, int g, int f4,
                                          float& ax, float& ay, float& az, float& aw) {
    int s = offs[row], e = offs[row + 1];
    s = __builtin_amdgcn_readfirstlane(s);
    e = __builtin_amdgcn_readfirstlane(e);
    ax = ay = az = aw = 0.f;
    for (int i = s; i < e; i += 8) {
        int i0 = i + g, i1 = i + 4 + g;
        int2 p0 = ecv[i0 < e ? i0 : (e - 1)];
        int2 p1 = ecv[i1 < e ? i1 : (e - 1)];
        float v0 = (i0 < e) ? __int_as_float(p0.y) : 0.f;
        float v1 = (i1 < e) ? __int_as_float(p1.y) : 0.f;
        float4 h0 = *(const float4*)(H + (size_t)p0.x * 64 + f4);
        float4 h1 = *(const float4*)(H + (size_t)p1.x * 64 + f4);
        ax = fmaf(v0, h0.x, ax); ay = fmaf(v0, h0.y, ay);
        az = fmaf(v0, h0.z, az); aw = fmaf(v0, h0.w, aw);
        ax = fmaf(v1, h1.x, ax); ay = fmaf(v1, h1.y, ay);
        az = fmaf(v1, h1.z, az); aw = fmaf(v1, h1.w, aw);
    }
#pragma unroll
    for (int d = 16; d <= 32; d <<= 1) {
        ax += __shfl_xor(ax, d, 64);
        ay += __shfl_xor(ay, d, 64);
        az += __shfl_xor(az, d, 64);
        aw += __shfl_xor(aw, d, 64);
    }
}

__global__ __launch_bounds__(256) void spmm_selu(const int* __restrict__ offsB,
                                                 const int2* __restrict__ ecvB,
                                                 const float* __restrict__ HB,
                                                 const float* __restrict__ bias,
                                                 float* __restrict__ outB,
                                                 int N, int E) {
    int gph = blockIdx.y;
    const int* offs = offsB + (size_t)gph * (N + 1);
    const int2* ecv = ecvB + (size_t)gph * E;
    const float* H = HB + (size_t)gph * N * 64;
    float* out = outB + (size_t)gph * N * 64;
    int row = blockIdx.x * 4 + (threadIdx.x >> 6);
    if (row >= N) return;
    int lane = threadIdx.x & 63;
    int g = lane >> 4, f4 = (lane & 15) * 4;
    float ax, ay, az, aw;
    spmm_row4(offs, ecv, H, row, g, f4, ax, ay, az, aw);
    float4 b = *(const float4*)(bias + f4);
    if (g == 0) {
        float4 o;
        o.x = selu_f(ax + b.x);
        o.y = selu_f(ay + b.y);
        o.z = selu_f(az + b.z);
        o.w = selu_f(aw + b.w);
        *(float4*)(out + (size_t)row * 64 + f4) = o;
    }
}

__global__ __launch_bounds__(256) void spmm_norm(const int* __restrict__ offsB,
                                                 const int2* __restrict__ ecvB,
                                                 const float* __restrict__ HB,
                                                 const float* __restrict__ bias,
                                                 float* __restrict__ outB,
                                                 int N, int E) {
    int gph = blockIdx.y;
    const int* offs = offsB + (size_t)gph * (N + 1);
    const int2* ecv = ecvB + (size_t)gph * E;
    const float* H = HB + (size_t)gph * N * 64;
    float* out = outB + (size_t)gph * N * 64;
    int row = blockIdx.x * 4 + (threadIdx.x >> 6);
    if (row >= N) return;
    int lane = threadIdx.x & 63;
    int g = lane >> 4, f4 = (lane & 15) * 4;
    float ax, ay, az, aw;
    spmm_row4(offs, ecv, H, row, g, f4, ax, ay, az, aw);
    float4 b = *(const float4*)(bias + f4);
    float zx = ax + b.x, zy = ay + b.y, zz = az + b.z, zw = aw + b.w;
    float s2 = zx * zx + zy * zy + zz * zz + zw * zw;
#pragma unroll
    for (int d = 1; d <= 8; d <<= 1) s2 += __shfl_xor(s2, d, 64);
    float inv = 1.0f / fmaxf(sqrtf(s2), 1e-12f);
    if (g == 0) {
        float4 o;
        o.x = zx * inv; o.y = zy * inv; o.z = zz * inv; o.w = zw * inv;
        *(float4*)(out + (size_t)row * 64 + f4) = o;
    }
}

extern "C" void kernel_launch(void* const* d_in, const int* in_sizes, int n_in,
                              void* d_out, int out_size, void* d_ws, size_t ws_size,
                              hipStream_t stream) {
    const int IN_DIM = 256, HID = 64;
    const int N = in_sizes[0] / IN_DIM;   // 100000
    const int E = in_sizes[2];            // 1200000

    const float* X1 = (const float*)d_in[0];
    const float* X2 = (const float*)d_in[1];
    const int*   r0 = (const int*)d_in[2];
    const int*   c0 = (const int*)d_in[3];
    const float* v0 = (const float*)d_in[4];
    const int*   r1 = (const int*)d_in[5];
    const int*   c1 = (const int*)d_in[6];
    const float* v1 = (const float*)d_in[7];
    const float* W1 = (const float*)d_in[8];
    const float* b1 = (const float*)d_in[9];
    const float* W2 = (const float*)d_in[10];
    const float* b2 = (const float*)d_in[11];
    float* out = (float*)d_out;

    const int NB  = (N + RPB - 1) / RPB;      // 196
    const int nbA = (E + EPB - 1) / EPB;      // 293
    const int M   = NB * nbA;
    const int nbScanM = (M + 1023) / 1024;    // 57
    const int nbGemm = (N + 63) / 64;         // 1563
    const int nbRow  = (N + 3) / 4;           // 25000

    auto align16 = [](char* p) { return (char*)(((uintptr_t)p + 15) & ~(uintptr_t)15); };
    char* w = (char*)d_ws;
    float* bufA   = (float*)w; w += (size_t)2 * N * HID * sizeof(float);
    float* bufB   = (float*)w; w += (size_t)2 * N * HID * sizeof(float);
    w = align16(w);
    int2*  ecv    = (int2*)w;  w += (size_t)2 * E * sizeof(int2);
    w = align16(w);
    int*   cntT   = (int*)w;   w += (size_t)2 * M * sizeof(int);
    w = align16(w);
    int*   csOffs = (int*)w;   w += (size_t)2 * (M + 1) * sizeof(int);
    w = align16(w);
    int*   offs   = (int*)w;   w += (size_t)2 * (N + 1) * sizeof(int);
    w = align16(w);
    int*   partials = (int*)w; w += 2 * 512 * sizeof(int);
    w = align16(w);
    short* w1th = (short*)w;   w += (size_t)64 * IN_DIM * sizeof(short);
    short* w1tl = (short*)w;   w += (size_t)64 * IN_DIM * sizeof(short);
    short* w2th = (short*)w;   w += (size_t)64 * HID * sizeof(short);
    short* w2tl = (short*)w;   w += (size_t)64 * HID * sizeof(short);
    // ecvA (2 graphs, 19.2MB) aliases bufA (51.2MB): dead before gemm1 writes
    int2*  ecvA = (int2*)bufA;

    // weight prep (one tiny dispatch)
    prep_w2<<<(IN_DIM * 64 + HID * 64 + 255) / 256, 256, 0, stream>>>(
        W1, w1th, w1tl, W2, w2th, w2tl);

    // CSR build, both graphs per dispatch
    bucket_hist<<<dim3(nbA, 2), 256, 0, stream>>>(r0, r1, cntT, E, nbA, NB, M);
    scan_a<<<dim3(nbScanM, 2), 256, 0, stream>>>(cntT, csOffs, partials, M);
    scan_b<<<dim3(1, 2), 128, 0, stream>>>(partials, nbScanM);
    scan_c<<<dim3(nbScanM, 2), 256, 0, stream>>>(csOffs, partials, M, E);
    coarse_scatter<<<dim3(nbA, 2), 256, 0, stream>>>(r0, r1, c0, c1, v0, v1,
                                                     csOffs, ecvA, E, nbA, NB, M);
    fine_sort<<<dim3(NB, 2), 256, 0, stream>>>(csOffs, ecvA, ecv, offs, nbA, N, E, M);

    // layer 1, both graphs
    gemm_mfma<256><<<dim3(nbGemm, 2), 256, 0, stream>>>(
        X1, X2, w1th, w1tl, bufA, bufA + (size_t)N * HID, N);
    spmm_selu<<<dim3(nbRow, 2), 256, 0, stream>>>(offs, ecv, bufA, b1, bufB, N, E);

    // layer 2, both graphs
    gemm_mfma<64><<<dim3(nbGemm, 2), 256, 0, stream>>>(
        bufB, bufB + (size_t)N * HID, w2th, w2tl, bufA, bufA + (size_t)N * HID, N);
    spmm_norm<<<dim3(nbRow, 2), 256, 0, stream>>>(offs, ecv, bufA, b2, out, N, E);
}

// Round 4
// 520.200 us; speedup vs baseline: 1.5243x; 1.0334x over previous
//
#include <hip/hip_runtime.h>
#include <hip/hip_bf16.h>

// GCN 2-layer forward, two graphs, shared weights.
// R4: gemm2 fused into spmm_selu's epilogue (spmm_selu_w2): block owns 16 rows,
//     gathers+selu -> LDS (split-bf16), one barrier, 6 MFMAs/wave compute
//     Z1@W2 (W2 fragments read from global; L1-resident, identical across
//     blocks). Removes the gemm<64> dispatch + its 51MB bufB re-read.
//     Gather loop widened 8->16 edges/iter (4 gathers in flight per lane).
// CSR build + gemm1 + spmm_norm: unchanged from verified R3 (batched y=2).

#define RPB 512
#define EPB 4096
#define MAXB 8192

typedef __attribute__((ext_vector_type(8))) short short8;
typedef __attribute__((ext_vector_type(4))) short short4v;
typedef __attribute__((ext_vector_type(4))) float f32x4;

__device__ __forceinline__ float selu_f(float x) {
    const float scale = 1.0507009873554805f;
    const float alpha = 1.6732632423543772f;
    return x > 0.0f ? scale * x : scale * alpha * (__expf(x) - 1.0f);
}

__device__ __forceinline__ short f2bf(float x) {   // RNE truncate fp32->bf16
    unsigned u = __float_as_uint(x);
    u += 0x7FFF + ((u >> 16) & 1);
    return (short)(u >> 16);
}
__device__ __forceinline__ float bf2f(short h) {
    return __uint_as_float(((unsigned)(unsigned short)h) << 16);
}

// ---------------- scan (batched over graphs via blockIdx.y) ----------------
__global__ void scan_a(const int* __restrict__ countsB, int* __restrict__ offsB,
                       int* __restrict__ partialsB, int N) {
    const int* counts = countsB + (size_t)blockIdx.y * N;
    int* offs = offsB + (size_t)blockIdx.y * (N + 1);
    int* partials = partialsB + (size_t)blockIdx.y * 512;
    __shared__ int sh[256];
    int tid = threadIdx.x;
    int base = blockIdx.x * 1024 + tid * 4;
    int4 c = make_int4(0, 0, 0, 0);
    if (base + 3 < N) {
        c = *(const int4*)(counts + base);
    } else {
        if (base + 0 < N) c.x = counts[base + 0];
        if (base + 1 < N) c.y = counts[base + 1];
        if (base + 2 < N) c.z = counts[base + 2];
        if (base + 3 < N) c.w = counts[base + 3];
    }
    int tsum = c.x + c.y + c.z + c.w;
    sh[tid] = tsum;
    __syncthreads();
    int val = tsum;
    for (int d = 1; d < 256; d <<= 1) {
        int t = (tid >= d) ? sh[tid - d] : 0;
        __syncthreads();
        val += t;
        sh[tid] = val;
        __syncthreads();
    }
    int excl = val - tsum;
    int4 o;
    o.x = excl; o.y = o.x + c.x; o.z = o.y + c.y; o.w = o.z + c.z;
    if (base + 3 < N) {
        *(int4*)(offs + base) = o;
    } else {
        if (base + 0 < N) offs[base + 0] = o.x;
        if (base + 1 < N) offs[base + 1] = o.y;
        if (base + 2 < N) offs[base + 2] = o.z;
        if (base + 3 < N) offs[base + 3] = o.w;
    }
    if (tid == 255) partials[blockIdx.x] = val;
}

__global__ void scan_b(int* __restrict__ partialsB, int nb) {
    int* partials = partialsB + (size_t)blockIdx.y * 512;
    __shared__ int sh[128];
    int tid = threadIdx.x;
    int v = (tid < nb) ? partials[tid] : 0;
    sh[tid] = v;
    __syncthreads();
    int val = v;
    for (int d = 1; d < 128; d <<= 1) {
        int t = (tid >= d) ? sh[tid - d] : 0;
        __syncthreads();
        val += t;
        sh[tid] = val;
        __syncthreads();
    }
    if (tid < nb) partials[tid] = val - v;
}

__global__ void scan_c(int* __restrict__ offsB, const int* __restrict__ partialsB,
                       int N, int E) {
    int* offs = offsB + (size_t)blockIdx.y * (N + 1);
    const int* partials = partialsB + (size_t)blockIdx.y * 512;
    int tid = threadIdx.x;
    int base = blockIdx.x * 1024 + tid * 4;
    int add = partials[blockIdx.x];
    if (base + 3 < N) {
        int4 o = *(int4*)(offs + base);
        o.x += add; o.y += add; o.z += add; o.w += add;
        *(int4*)(offs + base) = o;
    } else {
        for (int t = 0; t < 4; t++)
            if (base + t < N) offs[base + t] += add;
    }
    if (blockIdx.x == 0 && tid == 0) offs[N] = E;
}

// ---------------- pass A1: coarse histogram (batched) ----------------
__global__ __launch_bounds__(256) void bucket_hist(const int* __restrict__ r0,
                                                   const int* __restrict__ r1,
                                                   int* __restrict__ cntTB,
                                                   int E, int nbA, int NB, int M) {
    const int* rows = blockIdx.y ? r1 : r0;
    int* cntT = cntTB + (size_t)blockIdx.y * M;
    __shared__ int cnt[256];
    int tid = threadIdx.x;
    cnt[tid] = 0;
    __syncthreads();
    int e0 = blockIdx.x * EPB;
#pragma unroll
    for (int k = 0; k < EPB / 256; k++) {
        int e = e0 + k * 256 + tid;
        if (e < E) atomicAdd(&cnt[rows[e] >> 9], 1);
    }
    __syncthreads();
    if (tid < NB) cntT[tid * nbA + blockIdx.x] = cnt[tid];
}

// ---------------- pass A2: block-local counting sort (batched) --------------
__global__ __launch_bounds__(256) void coarse_scatter(const int* __restrict__ r0,
                                                      const int* __restrict__ r1,
                                                      const int* __restrict__ c0,
                                                      const int* __restrict__ c1,
                                                      const float* __restrict__ v0,
                                                      const float* __restrict__ v1,
                                                      const int* __restrict__ csOffsB,
                                                      int2* __restrict__ ecvAB,
                                                      int E, int nbA, int NB, int M) {
    const int* rows = blockIdx.y ? r1 : r0;
    const int* cols = blockIdx.y ? c1 : c0;
    const float* vals = blockIdx.y ? v1 : v0;
    const int* csOffs = csOffsB + (size_t)blockIdx.y * (M + 1);
    int2* ecvA = ecvAB + (size_t)blockIdx.y * E;
    __shared__ int cnt[256];
    __shared__ int loc[256];
    __shared__ int gof[256];
    __shared__ int dstBase[EPB];
    __shared__ int2 eLDS[EPB];
    int tid = threadIdx.x, blk = blockIdx.x;
    int e0 = blk * EPB;
    cnt[tid] = 0;
    __syncthreads();
#pragma unroll
    for (int k = 0; k < EPB / 256; k++) {
        int e = e0 + k * 256 + tid;
        if (e < E) atomicAdd(&cnt[rows[e] >> 9], 1);
    }
    __syncthreads();
    int my = cnt[tid];
    loc[tid] = my;
    __syncthreads();
    int val = my;
    for (int d = 1; d < 256; d <<= 1) {
        int t = (tid >= d) ? loc[tid - d] : 0;
        __syncthreads();
        val += t;
        loc[tid] = val;
        __syncthreads();
    }
    int excl = val - my;
    loc[tid] = excl;
    cnt[tid] = excl;
    gof[tid] = (tid < NB) ? csOffs[tid * nbA + blk] : 0;
    __syncthreads();
#pragma unroll
    for (int k = 0; k < EPB / 256; k++) {
        int e = e0 + k * 256 + tid;
        if (e < E) {
            int r = rows[e];
            int b = r >> 9;
            int p = atomicAdd(&cnt[b], 1);
            eLDS[p] = make_int2(((r & (RPB - 1)) << 17) | cols[e],
                                __float_as_int(vals[e]));
            dstBase[p] = gof[b] - loc[b];
        }
    }
    __syncthreads();
    int nE = min(EPB, E - e0);
    for (int j = tid; j < nE; j += 256)
        ecvA[dstBase[j] + j] = eLDS[j];
}

// ---------------- pass B: per-bucket fine sort (batched) ----------------
__global__ __launch_bounds__(256) void fine_sort(const int* __restrict__ csOffsB,
                                                 const int2* __restrict__ ecvAB,
                                                 int2* __restrict__ ecvB,
                                                 int* __restrict__ offsB,
                                                 int nbA, int N, int E, int M) {
    const int* csOffs = csOffsB + (size_t)blockIdx.y * (M + 1);
    const int2* ecvA = ecvAB + (size_t)blockIdx.y * E;
    int2* ecv = ecvB + (size_t)blockIdx.y * E;
    int* offs = offsB + (size_t)blockIdx.y * (N + 1);
    __shared__ int rcnt[RPB], roff[RPB], rcur[RPB];
    __shared__ int sh[256];
    __shared__ int2 eLDS[MAXB];
    int b = blockIdx.x, tid = threadIdx.x;
    int bs = csOffs[b * nbA];
    int be = csOffs[(b + 1) * nbA];
    int cntE = be - bs;
    if (cntE > MAXB) cntE = MAXB;
    rcnt[tid] = 0;
    rcnt[tid + 256] = 0;
    __syncthreads();
    for (int j = tid; j < cntE; j += 256)
        atomicAdd(&rcnt[ecvA[bs + j].x >> 17], 1);
    __syncthreads();
    int a0 = rcnt[2 * tid], a1 = rcnt[2 * tid + 1];
    int ps = a0 + a1;
    sh[tid] = ps;
    __syncthreads();
    int val = ps;
    for (int d = 1; d < 256; d <<= 1) {
        int t = (tid >= d) ? sh[tid - d] : 0;
        __syncthreads();
        val += t;
        sh[tid] = val;
        __syncthreads();
    }
    int exclPair = val - ps;
    roff[2 * tid] = exclPair;
    roff[2 * tid + 1] = exclPair + a0;
    rcur[2 * tid] = exclPair;
    rcur[2 * tid + 1] = exclPair + a0;
    __syncthreads();
    int row0 = b * RPB;
    for (int t2 = tid; t2 < RPB; t2 += 256) {
        int row = row0 + t2;
        if (row <= N) offs[row] = bs + roff[t2];
    }
    if (b == 0 && tid == 0) offs[N] = E;
    for (int j = tid; j < cntE; j += 256) {
        int2 p = ecvA[bs + j];
        int pos = atomicAdd(&rcur[p.x >> 17], 1);
        if (pos < MAXB) eLDS[pos] = make_int2(p.x & 0x1FFFF, p.y);
    }
    __syncthreads();
    for (int j = tid; j < cntE; j += 256)
        ecv[bs + j] = eLDS[j];
}

// ---------------- weight prep: both weights in one dispatch ----------------
__global__ void prep_w2(const float* __restrict__ W1, short* __restrict__ th1,
                        short* __restrict__ tl1,
                        const float* __restrict__ W2, short* __restrict__ th2,
                        short* __restrict__ tl2) {
    int idx = blockIdx.x * 256 + threadIdx.x;
    const int n1 = 256 * 64;
    if (idx < n1) {
        int k = idx >> 6, n = idx & 63;
        float x = W1[idx];
        short h = f2bf(x);
        short l = f2bf(x - bf2f(h));
        th1[n * 256 + k] = h;
        tl1[n * 256 + k] = l;
    } else if (idx - n1 < 64 * 64) {
        int i2 = idx - n1;
        int k = i2 >> 6, n = i2 & 63;
        float x = W2[i2];
        short h = f2bf(x);
        short l = f2bf(x - bf2f(h));
        th2[n * 64 + k] = h;
        tl2[n * 64 + k] = l;
    }
}

// ---------------- MFMA GEMM: C[M,64] = A[M,K] @ W[K,64], batched ------------
// Block: 256 thr = 4 waves; tile 64 rows x 64 cols. K-chunks of 64 with
// register A-prefetch (reg loads not drained by __syncthreads).
template<int K>
__global__ __launch_bounds__(256) void gemm_mfma(const float* __restrict__ A0,
                                                 const float* __restrict__ A1,
                                                 const short* __restrict__ Wth,
                                                 const short* __restrict__ Wtl,
                                                 float* __restrict__ C0,
                                                 float* __restrict__ C1, int M) {
    constexpr int NC = K / 64;
    const float* A = blockIdx.y ? A1 : A0;
    float* C = blockIdx.y ? C1 : C0;
    __shared__ short Ah[64 * 72], Al[64 * 72];   // [row][k], stride 72 (pad 8)
    __shared__ short Wh[64 * 72], Wl[64 * 72];   // [n][k],   stride 72
    int tid = threadIdx.x;
    int wave = tid >> 6, lane = tid & 63;
    int m = lane & 15, q = lane >> 4;
    int row0 = blockIdx.x * 64;
    int ai = tid >> 4;            // row within quarter: 0..15
    int aj = (tid & 15) * 4;      // col: 0,4,..,60
    f32x4 acc[4] = {{0.f, 0.f, 0.f, 0.f}, {0.f, 0.f, 0.f, 0.f},
                    {0.f, 0.f, 0.f, 0.f}, {0.f, 0.f, 0.f, 0.f}};

    // prologue: A chunk 0 -> regs
    float4 ga[4];
#pragma unroll
    for (int v = 0; v < 4; v++) {
        int gr = row0 + v * 16 + ai;
        ga[v] = make_float4(0.f, 0.f, 0.f, 0.f);
        if (gr < M) ga[v] = *(const float4*)(A + (size_t)gr * K + aj);
    }

#pragma unroll
    for (int c = 0; c < NC; c++) {
        // W chunk c -> regs (issued first; L2-resident, hides under convert)
        short4v whv[4], wlv[4];
#pragma unroll
        for (int v = 0; v < 4; v++) {
            size_t wo = (size_t)(v * 16 + ai) * K + c * 64 + aj;
            whv[v] = *(const short4v*)(Wth + wo);
            wlv[v] = *(const short4v*)(Wtl + wo);
        }
        // prefetch next A chunk -> regs (hides HBM latency under this chunk)
        float4 gan[4];
        if (c + 1 < NC) {
#pragma unroll
            for (int v = 0; v < 4; v++) {
                int gr = row0 + v * 16 + ai;
                gan[v] = make_float4(0.f, 0.f, 0.f, 0.f);
                if (gr < M)
                    gan[v] = *(const float4*)(A + (size_t)gr * K + (c + 1) * 64 + aj);
            }
        }
        // convert current A (regs) -> split-bf16 LDS
#pragma unroll
        for (int v = 0; v < 4; v++) {
            int r = v * 16 + ai;
            float f[4] = {ga[v].x, ga[v].y, ga[v].z, ga[v].w};
            short4v h, l;
#pragma unroll
            for (int j = 0; j < 4; j++) {
                short hh = f2bf(f[j]);
                h[j] = hh;
                l[j] = f2bf(f[j] - bf2f(hh));
            }
            *(short4v*)(&Ah[r * 72 + aj]) = h;
            *(short4v*)(&Al[r * 72 + aj]) = l;
        }
        // W regs -> LDS
#pragma unroll
        for (int v = 0; v < 4; v++) {
            int n = v * 16 + ai;
            *(short4v*)(&Wh[n * 72 + aj]) = whv[v];
            *(short4v*)(&Wl[n * 72 + aj]) = wlv[v];
        }
        __syncthreads();
        int ar = (16 * wave + m) * 72;
        short8 ah0 = *(const short8*)(&Ah[ar + q * 8]);
        short8 ah1 = *(const short8*)(&Ah[ar + 32 + q * 8]);
        short8 al0 = *(const short8*)(&Al[ar + q * 8]);
        short8 al1 = *(const short8*)(&Al[ar + 32 + q * 8]);
#pragma unroll
        for (int nt = 0; nt < 4; nt++) {
            int nb = (nt * 16 + m) * 72;
            short8 bh0 = *(const short8*)(&Wh[nb + q * 8]);
            short8 bh1 = *(const short8*)(&Wh[nb + 32 + q * 8]);
            short8 bl0 = *(const short8*)(&Wl[nb + q * 8]);
            short8 bl1 = *(const short8*)(&Wl[nb + 32 + q * 8]);
            acc[nt] = __builtin_amdgcn_mfma_f32_16x16x32_bf16(ah0, bh0, acc[nt], 0, 0, 0);
            acc[nt] = __builtin_amdgcn_mfma_f32_16x16x32_bf16(al0, bh0, acc[nt], 0, 0, 0);
            acc[nt] = __builtin_amdgcn_mfma_f32_16x16x32_bf16(ah0, bl0, acc[nt], 0, 0, 0);
            acc[nt] = __builtin_amdgcn_mfma_f32_16x16x32_bf16(ah1, bh1, acc[nt], 0, 0, 0);
            acc[nt] = __builtin_amdgcn_mfma_f32_16x16x32_bf16(al1, bh1, acc[nt], 0, 0, 0);
            acc[nt] = __builtin_amdgcn_mfma_f32_16x16x32_bf16(ah1, bl1, acc[nt], 0, 0, 0);
        }
        if (c + 1 < NC) {
            __syncthreads();       // protect LDS before next chunk's overwrite
#pragma unroll
            for (int v = 0; v < 4; v++) ga[v] = gan[v];
        }
    }
    // epilogue: C/D layout col=lane&15, row=q*4+reg
#pragma unroll
    for (int nt = 0; nt < 4; nt++) {
#pragma unroll
        for (int r = 0; r < 4; r++) {
            int grow = row0 + 16 * wave + q * 4 + r;
            if (grow < M) C[(size_t)grow * 64 + nt * 16 + m] = acc[nt][r];
        }
    }
}

// ---------------- SpMM core: one wave/row, 16 edges per iteration -----------
// lane = 16*g + t: group g handles edges i+g, i+4+g, i+8+g, i+12+g; thread t
// covers features 4t..4t+3. Butterfly (xor 16,32) leaves full sum in ALL lanes.
__device__ __forceinline__ void spmm_row4(const int* __restrict__ offs,
                                          const int2* __restrict__ ecv,
                                          const float* __restrict__ H,
                                          int row, int g, int f4,
                                          float& ax, float& ay, float& az, float& aw) {
    int s = offs[row], e = offs[row + 1];
    s = __builtin_amdgcn_readfirstlane(s);
    e = __builtin_amdgcn_readfirstlane(e);
    ax = ay = az = aw = 0.f;
    for (int i = s; i < e; i += 16) {
        int i0 = i + g, i1 = i + 4 + g, i2 = i + 8 + g, i3 = i + 12 + g;
        int2 p0 = ecv[i0 < e ? i0 : (e - 1)];
        int2 p1 = ecv[i1 < e ? i1 : (e - 1)];
        int2 p2 = ecv[i2 < e ? i2 : (e - 1)];
        int2 p3 = ecv[i3 < e ? i3 : (e - 1)];
        float v0 = (i0 < e) ? __int_as_float(p0.y) : 0.f;
        float v1 = (i1 < e) ? __int_as_float(p1.y) : 0.f;
        float v2 = (i2 < e) ? __int_as_float(p2.y) : 0.f;
        float v3 = (i3 < e) ? __int_as_float(p3.y) : 0.f;
        float4 h0 = *(const float4*)(H + (size_t)p0.x * 64 + f4);
        float4 h1 = *(const float4*)(H + (size_t)p1.x * 64 + f4);
        float4 h2 = *(const float4*)(H + (size_t)p2.x * 64 + f4);
        float4 h3 = *(const float4*)(H + (size_t)p3.x * 64 + f4);
        ax = fmaf(v0, h0.x, ax); ay = fmaf(v0, h0.y, ay);
        az = fmaf(v0, h0.z, az); aw = fmaf(v0, h0.w, aw);
        ax = fmaf(v1, h1.x, ax); ay = fmaf(v1, h1.y, ay);
        az = fmaf(v1, h1.z, az); aw = fmaf(v1, h1.w, aw);
        ax = fmaf(v2, h2.x, ax); ay = fmaf(v2, h2.y, ay);
        az = fmaf(v2, h2.z, az); aw = fmaf(v2, h2.w, aw);
        ax = fmaf(v3, h3.x, ax); ay = fmaf(v3, h3.y, ay);
        az = fmaf(v3, h3.z, az); aw = fmaf(v3, h3.w, aw);
    }
#pragma unroll
    for (int d = 16; d <= 32; d <<= 1) {
        ax += __shfl_xor(ax, d, 64);
        ay += __shfl_xor(ay, d, 64);
        az += __shfl_xor(az, d, 64);
        aw += __shfl_xor(aw, d, 64);
    }
}

// ---------------- fused: Z1 = selu(A@H + b1); Y = Z1 @ W2 -> out ------------
// Block owns 16 rows: 4 waves x 4 rows sequential gather, selu'd rows staged
// in LDS as split-bf16 [16][72]; one barrier; each wave computes one 16x16
// n-tile of Z1@W2 (6 MFMAs, W2 frags from global = L1-resident).
__global__ __launch_bounds__(256) void spmm_selu_w2(const int* __restrict__ offsB,
                                                    const int2* __restrict__ ecvB,
                                                    const float* __restrict__ HB,
                                                    const float* __restrict__ bias,
                                                    const short* __restrict__ w2th,
                                                    const short* __restrict__ w2tl,
                                                    float* __restrict__ outB,
                                                    int N, int E) {
    int gph = blockIdx.y;
    const int* offs = offsB + (size_t)gph * (N + 1);
    const int2* ecv = ecvB + (size_t)gph * E;
    const float* H = HB + (size_t)gph * N * 64;
    float* out = outB + (size_t)gph * N * 64;
    __shared__ short Zh[16 * 72], Zl[16 * 72];
    int tid = threadIdx.x, wave = tid >> 6, lane = tid & 63;
    int g = lane >> 4, f4 = (lane & 15) * 4;
    int rbase = blockIdx.x * 16;
    float4 b = *(const float4*)(bias + f4);
#pragma unroll
    for (int rr = 0; rr < 4; rr++) {
        int lr = wave * 4 + rr;
        int row = rbase + lr;
        if (row < N) {
            float ax, ay, az, aw;
            spmm_row4(offs, ecv, H, row, g, f4, ax, ay, az, aw);
            if (g == 0) {
                float zx = selu_f(ax + b.x);
                float zy = selu_f(ay + b.y);
                float zz = selu_f(az + b.z);
                float zw = selu_f(aw + b.w);
                short4v h, l;
                h.x = f2bf(zx); l.x = f2bf(zx - bf2f(h.x));
                h.y = f2bf(zy); l.y = f2bf(zy - bf2f(h.y));
                h.z = f2bf(zz); l.z = f2bf(zz - bf2f(h.z));
                h.w = f2bf(zw); l.w = f2bf(zw - bf2f(h.w));
                *(short4v*)(&Zh[lr * 72 + f4]) = h;
                *(short4v*)(&Zl[lr * 72 + f4]) = l;
            }
        } else if (g == 0) {
            short4v zv = {0, 0, 0, 0};
            *(short4v*)(&Zh[lr * 72 + f4]) = zv;
            *(short4v*)(&Zl[lr * 72 + f4]) = zv;
        }
    }
    __syncthreads();
    // MFMA phase: wave -> n-tile = wave (cols wave*16..+15), K=64 = 2 k-steps
    int m_ = lane & 15, q = lane >> 4;
    int ar = m_ * 72;
    short8 ah0 = *(const short8*)(&Zh[ar + q * 8]);
    short8 ah1 = *(const short8*)(&Zh[ar + 32 + q * 8]);
    short8 al0 = *(const short8*)(&Zl[ar + q * 8]);
    short8 al1 = *(const short8*)(&Zl[ar + 32 + q * 8]);
    const short* bhp = w2th + (size_t)(wave * 16 + m_) * 64;
    const short* blp = w2tl + (size_t)(wave * 16 + m_) * 64;
    short8 bh0 = *(const short8*)(bhp + q * 8);
    short8 bh1 = *(const short8*)(bhp + 32 + q * 8);
    short8 bl0 = *(const short8*)(blp + q * 8);
    short8 bl1 = *(const short8*)(blp + 32 + q * 8);
    f32x4 acc = {0.f, 0.f, 0.f, 0.f};
    acc = __builtin_amdgcn_mfma_f32_16x16x32_bf16(ah0, bh0, acc, 0, 0, 0);
    acc = __builtin_amdgcn_mfma_f32_16x16x32_bf16(al0, bh0, acc, 0, 0, 0);
    acc = __builtin_amdgcn_mfma_f32_16x16x32_bf16(ah0, bl0, acc, 0, 0, 0);
    acc = __builtin_amdgcn_mfma_f32_16x16x32_bf16(ah1, bh1, acc, 0, 0, 0);
    acc = __builtin_amdgcn_mfma_f32_16x16x32_bf16(al1, bh1, acc, 0, 0, 0);
    acc = __builtin_amdgcn_mfma_f32_16x16x32_bf16(ah1, bl1, acc, 0, 0, 0);
    // C/D layout: col = lane&15, row = q*4 + r
#pragma unroll
    for (int r = 0; r < 4; r++) {
        int grow = rbase + q * 4 + r;
        if (grow < N) out[(size_t)grow * 64 + wave * 16 + m_] = acc[r];
    }
}

// ---------------- spmm_norm: Z2 = A@Y + b2, row-L2-normalize ----------------
__global__ __launch_bounds__(256) void spmm_norm(const int* __restrict__ offsB,
                                                 const int2* __restrict__ ecvB,
                                                 const float* __restrict__ HB,
                                                 const float* __restrict__ bias,
                                                 float* __restrict__ outB,
                                                 int N, int E) {
    int gph = blockIdx.y;
    const int* offs = offsB + (size_t)gph * (N + 1);
    const int2* ecv = ecvB + (size_t)gph * E;
    const float* H = HB + (size_t)gph * N * 64;
    float* out = outB + (size_t)gph * N * 64;
    int row = blockIdx.x * 4 + (threadIdx.x >> 6);
    if (row >= N) return;
    int lane = threadIdx.x & 63;
    int g = lane >> 4, f4 = (lane & 15) * 4;
    float ax, ay, az, aw;
    spmm_row4(offs, ecv, H, row, g, f4, ax, ay, az, aw);
    float4 b = *(const float4*)(bias + f4);
    float zx = ax + b.x, zy = ay + b.y, zz = az + b.z, zw = aw + b.w;
    float s2 = zx * zx + zy * zy + zz * zz + zw * zw;
#pragma unroll
    for (int d = 1; d <= 8; d <<= 1) s2 += __shfl_xor(s2, d, 64);
    float inv = 1.0f / fmaxf(sqrtf(s2), 1e-12f);
    if (g == 0) {
        float4 o;
        o.x = zx * inv; o.y = zy * inv; o.z = zz * inv; o.w = zw * inv;
        *(float4*)(out + (size_t)row * 64 + f4) = o;
    }
}

extern "C" void kernel_launch(void* const* d_in, const int* in_sizes, int n_in,
                              void* d_out, int out_size, void* d_ws, size_t ws_size,
                              hipStream_t stream) {
    const int IN_DIM = 256, HID = 64;
    const int N = in_sizes[0] / IN_DIM;   // 100000
    const int E = in_sizes[2];            // 1200000

    const float* X1 = (const float*)d_in[0];
    const float* X2 = (const float*)d_in[1];
    const int*   r0 = (const int*)d_in[2];
    const int*   c0 = (const int*)d_in[3];
    const float* v0 = (const float*)d_in[4];
    const int*   r1 = (const int*)d_in[5];
    const int*   c1 = (const int*)d_in[6];
    const float* v1 = (const float*)d_in[7];
    const float* W1 = (const float*)d_in[8];
    const float* b1 = (const float*)d_in[9];
    const float* W2 = (const float*)d_in[10];
    const float* b2 = (const float*)d_in[11];
    float* out = (float*)d_out;

    const int NB  = (N + RPB - 1) / RPB;      // 196
    const int nbA = (E + EPB - 1) / EPB;      // 293
    const int M   = NB * nbA;
    const int nbScanM = (M + 1023) / 1024;    // 57
    const int nbGemm = (N + 63) / 64;         // 1563
    const int nbRow  = (N + 3) / 4;           // 25000
    const int nbFuse = (N + 15) / 16;         // 6250

    auto align16 = [](char* p) { return (char*)(((uintptr_t)p + 15) & ~(uintptr_t)15); };
    char* w = (char*)d_ws;
    float* bufA   = (float*)w; w += (size_t)2 * N * HID * sizeof(float);
    float* bufB   = (float*)w; w += (size_t)2 * N * HID * sizeof(float);
    w = align16(w);
    int2*  ecv    = (int2*)w;  w += (size_t)2 * E * sizeof(int2);
    w = align16(w);
    int*   cntT   = (int*)w;   w += (size_t)2 * M * sizeof(int);
    w = align16(w);
    int*   csOffs = (int*)w;   w += (size_t)2 * (M + 1) * sizeof(int);
    w = align16(w);
    int*   offs   = (int*)w;   w += (size_t)2 * (N + 1) * sizeof(int);
    w = align16(w);
    int*   partials = (int*)w; w += 2 * 512 * sizeof(int);
    w = align16(w);
    short* w1th = (short*)w;   w += (size_t)64 * IN_DIM * sizeof(short);
    short* w1tl = (short*)w;   w += (size_t)64 * IN_DIM * sizeof(short);
    short* w2th = (short*)w;   w += (size_t)64 * HID * sizeof(short);
    short* w2tl = (short*)w;   w += (size_t)64 * HID * sizeof(short);
    // ecvA (2 graphs, 19.2MB) aliases bufA (51.2MB): dead before gemm1 writes
    int2*  ecvA = (int2*)bufA;

    // weight prep (one tiny dispatch)
    prep_w2<<<(IN_DIM * 64 + HID * 64 + 255) / 256, 256, 0, stream>>>(
        W1, w1th, w1tl, W2, w2th, w2tl);

    // CSR build, both graphs per dispatch
    bucket_hist<<<dim3(nbA, 2), 256, 0, stream>>>(r0, r1, cntT, E, nbA, NB, M);
    scan_a<<<dim3(nbScanM, 2), 256, 0, stream>>>(cntT, csOffs, partials, M);
    scan_b<<<dim3(1, 2), 128, 0, stream>>>(partials, nbScanM);
    scan_c<<<dim3(nbScanM, 2), 256, 0, stream>>>(csOffs, partials, M, E);
    coarse_scatter<<<dim3(nbA, 2), 256, 0, stream>>>(r0, r1, c0, c1, v0, v1,
                                                     csOffs, ecvA, E, nbA, NB, M);
    fine_sort<<<dim3(NB, 2), 256, 0, stream>>>(csOffs, ecvA, ecv, offs, nbA, N, E, M);

    // layer 1 GEMM: H = X @ W1 (both graphs)
    gemm_mfma<256><<<dim3(nbGemm, 2), 256, 0, stream>>>(
        X1, X2, w1th, w1tl, bufA, bufA + (size_t)N * HID, N);
    // fused: Z1 = selu(A@H + b1); Y = Z1@W2 -> bufB (gemm2 dispatch eliminated)
    spmm_selu_w2<<<dim3(nbFuse, 2), 256, 0, stream>>>(offs, ecv, bufA, b1,
                                                      w2th, w2tl, bufB, N, E);
    // layer 2 aggregation + bias + L2 normalize -> out
    spmm_norm<<<dim3(nbRow, 2), 256, 0, stream>>>(offs, ecv, bufB, b2, out, N, E);
}

// Round 5
// 504.526 us; speedup vs baseline: 1.5716x; 1.0311x over previous
//
#include <hip/hip_runtime.h>
#include <hip/hip_bf16.h>

// GCN 2-layer forward, two graphs, shared weights.
// R5: gemm1 overlapped with the CSR build via role-split fat kernels.
//     gemm1's 64-row tiles are independent of everything; the CSR chain
//     (hist -> scan -> scatter -> sort) is independent of gemm1. Single-stream
//     + graph capture forbids multi-stream fork (hipEvent* banned), so each
//     CSR stage dispatch carries a proportional slice of gemm1 tiles in its
//     high blockIdx range. LDS per fat = max(role LDS).
// GEMM: MFMA 16x16x32 bf16 split-bf16 3-term, 64x64 tile, LDS staging,
//     register A-prefetch across K-chunks (verified R2-R4 numerics).
// spmm_selu_w2: fused Z1=selu(A@H+b1); Y=Z1@W2 (R4).
// spmm_norm: layer-2 aggregation + L2 normalize.

#define RPB 512
#define EPB 4096
#define MAXB 8192

typedef __attribute__((ext_vector_type(8))) short short8;
typedef __attribute__((ext_vector_type(4))) short short4v;
typedef __attribute__((ext_vector_type(4))) float f32x4;

#define GEMM_LDS 36864   // 4 * 64*72 shorts
#define SCAT_LDS 52224   // 3*1KB + 16KB + 32KB
#define SORT_LDS 72704   // 3*2KB + 1KB + 64KB

__device__ __forceinline__ float selu_f(float x) {
    const float scale = 1.0507009873554805f;
    const float alpha = 1.6732632423543772f;
    return x > 0.0f ? scale * x : scale * alpha * (__expf(x) - 1.0f);
}

__device__ __forceinline__ short f2bf(float x) {   // RNE truncate fp32->bf16
    unsigned u = __float_as_uint(x);
    u += 0x7FFF + ((u >> 16) & 1);
    return (short)(u >> 16);
}
__device__ __forceinline__ float bf2f(short h) {
    return __uint_as_float(((unsigned)(unsigned short)h) << 16);
}

// ---------------- scan (batched over graphs via blockIdx.y) ----------------
__global__ void scan_a(const int* __restrict__ countsB, int* __restrict__ offsB,
                       int* __restrict__ partialsB, int N) {
    const int* counts = countsB + (size_t)blockIdx.y * N;
    int* offs = offsB + (size_t)blockIdx.y * (N + 1);
    int* partials = partialsB + (size_t)blockIdx.y * 512;
    __shared__ int sh[256];
    int tid = threadIdx.x;
    int base = blockIdx.x * 1024 + tid * 4;
    int4 c = make_int4(0, 0, 0, 0);
    if (base + 3 < N) {
        c = *(const int4*)(counts + base);
    } else {
        if (base + 0 < N) c.x = counts[base + 0];
        if (base + 1 < N) c.y = counts[base + 1];
        if (base + 2 < N) c.z = counts[base + 2];
        if (base + 3 < N) c.w = counts[base + 3];
    }
    int tsum = c.x + c.y + c.z + c.w;
    sh[tid] = tsum;
    __syncthreads();
    int val = tsum;
    for (int d = 1; d < 256; d <<= 1) {
        int t = (tid >= d) ? sh[tid - d] : 0;
        __syncthreads();
        val += t;
        sh[tid] = val;
        __syncthreads();
    }
    int excl = val - tsum;
    int4 o;
    o.x = excl; o.y = o.x + c.x; o.z = o.y + c.y; o.w = o.z + c.z;
    if (base + 3 < N) {
        *(int4*)(offs + base) = o;
    } else {
        if (base + 0 < N) offs[base + 0] = o.x;
        if (base + 1 < N) offs[base + 1] = o.y;
        if (base + 2 < N) offs[base + 2] = o.z;
        if (base + 3 < N) offs[base + 3] = o.w;
    }
    if (tid == 255) partials[blockIdx.x] = val;
}

__global__ void scan_b(int* __restrict__ partialsB, int nb) {
    int* partials = partialsB + (size_t)blockIdx.y * 512;
    __shared__ int sh[128];
    int tid = threadIdx.x;
    int v = (tid < nb) ? partials[tid] : 0;
    sh[tid] = v;
    __syncthreads();
    int val = v;
    for (int d = 1; d < 128; d <<= 1) {
        int t = (tid >= d) ? sh[tid - d] : 0;
        __syncthreads();
        val += t;
        sh[tid] = val;
        __syncthreads();
    }
    if (tid < nb) partials[tid] = val - v;
}

__global__ void scan_c(int* __restrict__ offsB, const int* __restrict__ partialsB,
                       int N, int E) {
    int* offs = offsB + (size_t)blockIdx.y * (N + 1);
    const int* partials = partialsB + (size_t)blockIdx.y * 512;
    int tid = threadIdx.x;
    int base = blockIdx.x * 1024 + tid * 4;
    int add = partials[blockIdx.x];
    if (base + 3 < N) {
        int4 o = *(int4*)(offs + base);
        o.x += add; o.y += add; o.z += add; o.w += add;
        *(int4*)(offs + base) = o;
    } else {
        for (int t = 0; t < 4; t++)
            if (base + t < N) offs[base + t] += add;
    }
    if (blockIdx.x == 0 && tid == 0) offs[N] = E;
}

// ================= device role bodies (called from fat kernels) =============

// ---- role: coarse histogram (1KB LDS) ----
__device__ __forceinline__ void role_hist(const int* __restrict__ rows,
                                          int* __restrict__ cntT,
                                          int E, int nbA, int NB, int bx,
                                          int* cnt) {
    int tid = threadIdx.x;
    cnt[tid] = 0;
    __syncthreads();
    int e0 = bx * EPB;
#pragma unroll
    for (int k = 0; k < EPB / 256; k++) {
        int e = e0 + k * 256 + tid;
        if (e < E) atomicAdd(&cnt[rows[e] >> 9], 1);
    }
    __syncthreads();
    if (tid < NB) cntT[tid * nbA + bx] = cnt[tid];
}

// ---- role: block-local counting sort (52KB LDS) ----
__device__ __forceinline__ void role_scatter(const int* __restrict__ rows,
                                             const int* __restrict__ cols,
                                             const float* __restrict__ vals,
                                             const int* __restrict__ csOffs,
                                             int2* __restrict__ ecvA,
                                             int E, int nbA, int NB, int bx,
                                             char* smem) {
    int* cnt = (int*)smem;                 // 256
    int* loc = cnt + 256;                  // 256
    int* gof = loc + 256;                  // 256
    int* dstBase = gof + 256;              // EPB
    int2* eLDS = (int2*)(dstBase + EPB);   // EPB int2
    int tid = threadIdx.x;
    int e0 = bx * EPB;
    cnt[tid] = 0;
    __syncthreads();
#pragma unroll
    for (int k = 0; k < EPB / 256; k++) {
        int e = e0 + k * 256 + tid;
        if (e < E) atomicAdd(&cnt[rows[e] >> 9], 1);
    }
    __syncthreads();
    int my = cnt[tid];
    loc[tid] = my;
    __syncthreads();
    int val = my;
    for (int d = 1; d < 256; d <<= 1) {
        int t = (tid >= d) ? loc[tid - d] : 0;
        __syncthreads();
        val += t;
        loc[tid] = val;
        __syncthreads();
    }
    int excl = val - my;
    loc[tid] = excl;
    cnt[tid] = excl;
    gof[tid] = (tid < NB) ? csOffs[tid * nbA + bx] : 0;
    __syncthreads();
#pragma unroll
    for (int k = 0; k < EPB / 256; k++) {
        int e = e0 + k * 256 + tid;
        if (e < E) {
            int r = rows[e];
            int b = r >> 9;
            int p = atomicAdd(&cnt[b], 1);
            eLDS[p] = make_int2(((r & (RPB - 1)) << 17) | cols[e],
                                __float_as_int(vals[e]));
            dstBase[p] = gof[b] - loc[b];
        }
    }
    __syncthreads();
    int nE = min(EPB, E - e0);
    for (int j = tid; j < nE; j += 256)
        ecvA[dstBase[j] + j] = eLDS[j];
}

// ---- role: per-bucket fine sort (72.7KB LDS) ----
__device__ __forceinline__ void role_sort(const int* __restrict__ csOffs,
                                          const int2* __restrict__ ecvA,
                                          int2* __restrict__ ecv,
                                          int* __restrict__ offs,
                                          int nbA, int N, int E, int b,
                                          char* smem) {
    int* rcnt = (int*)smem;                // 512
    int* roff = rcnt + 512;                // 512
    int* rcur = roff + 512;                // 512
    int* sh   = rcur + 512;                // 256
    int2* eLDS = (int2*)(sh + 256);        // MAXB int2
    int tid = threadIdx.x;
    int bs = csOffs[b * nbA];
    int be = csOffs[(b + 1) * nbA];
    int cntE = be - bs;
    if (cntE > MAXB) cntE = MAXB;
    rcnt[tid] = 0;
    rcnt[tid + 256] = 0;
    __syncthreads();
    for (int j = tid; j < cntE; j += 256)
        atomicAdd(&rcnt[ecvA[bs + j].x >> 17], 1);
    __syncthreads();
    int a0 = rcnt[2 * tid], a1 = rcnt[2 * tid + 1];
    int ps = a0 + a1;
    sh[tid] = ps;
    __syncthreads();
    int val = ps;
    for (int d = 1; d < 256; d <<= 1) {
        int t = (tid >= d) ? sh[tid - d] : 0;
        __syncthreads();
        val += t;
        sh[tid] = val;
        __syncthreads();
    }
    int exclPair = val - ps;
    roff[2 * tid] = exclPair;
    roff[2 * tid + 1] = exclPair + a0;
    rcur[2 * tid] = exclPair;
    rcur[2 * tid + 1] = exclPair + a0;
    __syncthreads();
    int row0 = b * RPB;
    for (int t2 = tid; t2 < RPB; t2 += 256) {
        int row = row0 + t2;
        if (row <= N) offs[row] = bs + roff[t2];
    }
    if (b == 0 && tid == 0) offs[N] = E;
    for (int j = tid; j < cntE; j += 256) {
        int2 p = ecvA[bs + j];
        int pos = atomicAdd(&rcur[p.x >> 17], 1);
        if (pos < MAXB) eLDS[pos] = make_int2(p.x & 0x1FFFF, p.y);
    }
    __syncthreads();
    for (int j = tid; j < cntE; j += 256)
        ecv[bs + j] = eLDS[j];
}

// ---- role: one 64x64 tile of C = A[M,256] @ W[256,64] (36.9KB LDS) ----
__device__ __forceinline__ void role_gemm256(const float* __restrict__ A,
                                             const short* __restrict__ Wth,
                                             const short* __restrict__ Wtl,
                                             float* __restrict__ C, int M,
                                             int tile, char* smem) {
    constexpr int K = 256, NC = K / 64;
    short* Ah = (short*)smem;              // 64*72
    short* Al = Ah + 64 * 72;
    short* Wh = Al + 64 * 72;
    short* Wl = Wh + 64 * 72;
    int tid = threadIdx.x;
    int wave = tid >> 6, lane = tid & 63;
    int m = lane & 15, q = lane >> 4;
    int row0 = tile * 64;
    int ai = tid >> 4;
    int aj = (tid & 15) * 4;
    f32x4 acc[4] = {{0.f, 0.f, 0.f, 0.f}, {0.f, 0.f, 0.f, 0.f},
                    {0.f, 0.f, 0.f, 0.f}, {0.f, 0.f, 0.f, 0.f}};
    float4 ga[4];
#pragma unroll
    for (int v = 0; v < 4; v++) {
        int gr = row0 + v * 16 + ai;
        ga[v] = make_float4(0.f, 0.f, 0.f, 0.f);
        if (gr < M) ga[v] = *(const float4*)(A + (size_t)gr * K + aj);
    }
#pragma unroll
    for (int c = 0; c < NC; c++) {
        short4v whv[4], wlv[4];
#pragma unroll
        for (int v = 0; v < 4; v++) {
            size_t wo = (size_t)(v * 16 + ai) * K + c * 64 + aj;
            whv[v] = *(const short4v*)(Wth + wo);
            wlv[v] = *(const short4v*)(Wtl + wo);
        }
        float4 gan[4];
        if (c + 1 < NC) {
#pragma unroll
            for (int v = 0; v < 4; v++) {
                int gr = row0 + v * 16 + ai;
                gan[v] = make_float4(0.f, 0.f, 0.f, 0.f);
                if (gr < M)
                    gan[v] = *(const float4*)(A + (size_t)gr * K + (c + 1) * 64 + aj);
            }
        }
#pragma unroll
        for (int v = 0; v < 4; v++) {
            int r = v * 16 + ai;
            float f[4] = {ga[v].x, ga[v].y, ga[v].z, ga[v].w};
            short4v h, l;
#pragma unroll
            for (int j = 0; j < 4; j++) {
                short hh = f2bf(f[j]);
                h[j] = hh;
                l[j] = f2bf(f[j] - bf2f(hh));
            }
            *(short4v*)(&Ah[r * 72 + aj]) = h;
            *(short4v*)(&Al[r * 72 + aj]) = l;
        }
#pragma unroll
        for (int v = 0; v < 4; v++) {
            int n = v * 16 + ai;
            *(short4v*)(&Wh[n * 72 + aj]) = whv[v];
            *(short4v*)(&Wl[n * 72 + aj]) = wlv[v];
        }
        __syncthreads();
        int ar = (16 * wave + m) * 72;
        short8 ah0 = *(const short8*)(&Ah[ar + q * 8]);
        short8 ah1 = *(const short8*)(&Ah[ar + 32 + q * 8]);
        short8 al0 = *(const short8*)(&Al[ar + q * 8]);
        short8 al1 = *(const short8*)(&Al[ar + 32 + q * 8]);
#pragma unroll
        for (int nt = 0; nt < 4; nt++) {
            int nb = (nt * 16 + m) * 72;
            short8 bh0 = *(const short8*)(&Wh[nb + q * 8]);
            short8 bh1 = *(const short8*)(&Wh[nb + 32 + q * 8]);
            short8 bl0 = *(const short8*)(&Wl[nb + q * 8]);
            short8 bl1 = *(const short8*)(&Wl[nb + 32 + q * 8]);
            acc[nt] = __builtin_amdgcn_mfma_f32_16x16x32_bf16(ah0, bh0, acc[nt], 0, 0, 0);
            acc[nt] = __builtin_amdgcn_mfma_f32_16x16x32_bf16(al0, bh0, acc[nt], 0, 0, 0);
            acc[nt] = __builtin_amdgcn_mfma_f32_16x16x32_bf16(ah0, bl0, acc[nt], 0, 0, 0);
            acc[nt] = __builtin_amdgcn_mfma_f32_16x16x32_bf16(ah1, bh1, acc[nt], 0, 0, 0);
            acc[nt] = __builtin_amdgcn_mfma_f32_16x16x32_bf16(al1, bh1, acc[nt], 0, 0, 0);
            acc[nt] = __builtin_amdgcn_mfma_f32_16x16x32_bf16(ah1, bl1, acc[nt], 0, 0, 0);
        }
        if (c + 1 < NC) {
            __syncthreads();
#pragma unroll
            for (int v = 0; v < 4; v++) ga[v] = gan[v];
        }
    }
#pragma unroll
    for (int nt = 0; nt < 4; nt++) {
#pragma unroll
        for (int r = 0; r < 4; r++) {
            int grow = row0 + 16 * wave + q * 4 + r;
            if (grow < M) C[(size_t)grow * 64 + nt * 16 + m] = acc[nt][r];
        }
    }
}

// ================= fat kernels: CSR role (low blocks) + gemm slice ==========

__global__ __launch_bounds__(256) void fat_hist_gemm(
        const int* __restrict__ r0, const int* __restrict__ r1,
        int* __restrict__ cntTB, int E, int nbA, int NB, int Mcnt,
        const float* __restrict__ X1, const float* __restrict__ X2,
        const short* __restrict__ w1th, const short* __restrict__ w1tl,
        float* __restrict__ C0, float* __restrict__ C1, int Nn,
        int t0, int tcnt) {
    __shared__ __align__(16) char smem[GEMM_LDS];
    int id = blockIdx.x;
    int nCsr = 2 * nbA;
    if (id < nCsr) {
        int gph = id / nbA, bx = id % nbA;
        role_hist(gph ? r1 : r0, cntTB + (size_t)gph * Mcnt, E, nbA, NB, bx,
                  (int*)smem);
    } else {
        int gid = id - nCsr;
        int gph = gid / tcnt;
        int tile = t0 + gid - gph * tcnt;
        role_gemm256(gph ? X2 : X1, w1th, w1tl, gph ? C1 : C0, Nn, tile, smem);
    }
}

__global__ __launch_bounds__(256) void fat_scatter_gemm(
        const int* __restrict__ r0, const int* __restrict__ r1,
        const int* __restrict__ c0, const int* __restrict__ c1,
        const float* __restrict__ v0, const float* __restrict__ v1,
        const int* __restrict__ csOffsB, int2* __restrict__ ecvAB,
        int E, int nbA, int NB, int Mcnt,
        const float* __restrict__ X1, const float* __restrict__ X2,
        const short* __restrict__ w1th, const short* __restrict__ w1tl,
        float* __restrict__ C0, float* __restrict__ C1, int Nn,
        int t0, int tcnt) {
    __shared__ __align__(16) char smem[SCAT_LDS];
    int id = blockIdx.x;
    int nCsr = 2 * nbA;
    if (id < nCsr) {
        int gph = id / nbA, bx = id % nbA;
        role_scatter(gph ? r1 : r0, gph ? c1 : c0, gph ? v1 : v0,
                     csOffsB + (size_t)gph * (Mcnt + 1),
                     ecvAB + (size_t)gph * E, E, nbA, NB, bx, smem);
    } else {
        int gid = id - nCsr;
        int gph = gid / tcnt;
        int tile = t0 + gid - gph * tcnt;
        role_gemm256(gph ? X2 : X1, w1th, w1tl, gph ? C1 : C0, Nn, tile, smem);
    }
}

__global__ __launch_bounds__(256) void fat_sort_gemm(
        const int* __restrict__ csOffsB, const int2* __restrict__ ecvAB,
        int2* __restrict__ ecvB, int* __restrict__ offsB,
        int nbA, int N, int E, int Mcnt, int NB,
        const float* __restrict__ X1, const float* __restrict__ X2,
        const short* __restrict__ w1th, const short* __restrict__ w1tl,
        float* __restrict__ C0, float* __restrict__ C1, int Nn,
        int t0, int tcnt) {
    __shared__ __align__(16) char smem[SORT_LDS];
    int id = blockIdx.x;
    int nCsr = 2 * NB;
    if (id < nCsr) {
        int gph = id / NB, b = id % NB;
        role_sort(csOffsB + (size_t)gph * (Mcnt + 1),
                  ecvAB + (size_t)gph * E,
                  ecvB + (size_t)gph * E,
                  offsB + (size_t)gph * (N + 1),
                  nbA, N, E, b, smem);
    } else {
        int gid = id - nCsr;
        int gph = gid / tcnt;
        int tile = t0 + gid - gph * tcnt;
        role_gemm256(gph ? X2 : X1, w1th, w1tl, gph ? C1 : C0, Nn, tile, smem);
    }
}

// ---------------- weight prep: both weights in one dispatch ----------------
__global__ void prep_w2(const float* __restrict__ W1, short* __restrict__ th1,
                        short* __restrict__ tl1,
                        const float* __restrict__ W2, short* __restrict__ th2,
                        short* __restrict__ tl2) {
    int idx = blockIdx.x * 256 + threadIdx.x;
    const int n1 = 256 * 64;
    if (idx < n1) {
        int k = idx >> 6, n = idx & 63;
        float x = W1[idx];
        short h = f2bf(x);
        short l = f2bf(x - bf2f(h));
        th1[n * 256 + k] = h;
        tl1[n * 256 + k] = l;
    } else if (idx - n1 < 64 * 64) {
        int i2 = idx - n1;
        int k = i2 >> 6, n = i2 & 63;
        float x = W2[i2];
        short h = f2bf(x);
        short l = f2bf(x - bf2f(h));
        th2[n * 64 + k] = h;
        tl2[n * 64 + k] = l;
    }
}

// ---------------- SpMM core: one wave/row, 16 edges per iteration -----------
__device__ __forceinline__ void spmm_row4(const int* __restrict__ offs,
                                          const int2* __restrict__ ecv,
                                          const float* __restrict__ H,
                                          int row, int g, int f4,
                                          float& ax, float& ay, float& az, float& aw) {
    int s = offs[row], e = offs[row + 1];
    s = __builtin_amdgcn_readfirstlane(s);
    e = __builtin_amdgcn_readfirstlane(e);
    ax = ay = az = aw = 0.f;
    for (int i = s; i < e; i += 16) {
        int i0 = i + g, i1 = i + 4 + g, i2 = i + 8 + g, i3 = i + 12 + g;
        int2 p0 = ecv[i0 < e ? i0 : (e - 1)];
        int2 p1 = ecv[i1 < e ? i1 : (e - 1)];
        int2 p2 = ecv[i2 < e ? i2 : (e - 1)];
        int2 p3 = ecv[i3 < e ? i3 : (e - 1)];
        float v0 = (i0 < e) ? __int_as_float(p0.y) : 0.f;
        float v1 = (i1 < e) ? __int_as_float(p1.y) : 0.f;
        float v2 = (i2 < e) ? __int_as_float(p2.y) : 0.f;
        float v3 = (i3 < e) ? __int_as_float(p3.y) : 0.f;
        float4 h0 = *(const float4*)(H + (size_t)p0.x * 64 + f4);
        float4 h1 = *(const float4*)(H + (size_t)p1.x * 64 + f4);
        float4 h2 = *(const float4*)(H + (size_t)p2.x * 64 + f4);
        float4 h3 = *(const float4*)(H + (size_t)p3.x * 64 + f4);
        ax = fmaf(v0, h0.x, ax); ay = fmaf(v0, h0.y, ay);
        az = fmaf(v0, h0.z, az); aw = fmaf(v0, h0.w, aw);
        ax = fmaf(v1, h1.x, ax); ay = fmaf(v1, h1.y, ay);
        az = fmaf(v1, h1.z, az); aw = fmaf(v1, h1.w, aw);
        ax = fmaf(v2, h2.x, ax); ay = fmaf(v2, h2.y, ay);
        az = fmaf(v2, h2.z, az); aw = fmaf(v2, h2.w, aw);
        ax = fmaf(v3, h3.x, ax); ay = fmaf(v3, h3.y, ay);
        az = fmaf(v3, h3.z, az); aw = fmaf(v3, h3.w, aw);
    }
#pragma unroll
    for (int d = 16; d <= 32; d <<= 1) {
        ax += __shfl_xor(ax, d, 64);
        ay += __shfl_xor(ay, d, 64);
        az += __shfl_xor(az, d, 64);
        aw += __shfl_xor(aw, d, 64);
    }
}

// ---------------- fused: Z1 = selu(A@H + b1); Y = Z1 @ W2 -> out ------------
__global__ __launch_bounds__(256) void spmm_selu_w2(const int* __restrict__ offsB,
                                                    const int2* __restrict__ ecvB,
                                                    const float* __restrict__ HB,
                                                    const float* __restrict__ bias,
                                                    const short* __restrict__ w2th,
                                                    const short* __restrict__ w2tl,
                                                    float* __restrict__ outB,
                                                    int N, int E) {
    int gph = blockIdx.y;
    const int* offs = offsB + (size_t)gph * (N + 1);
    const int2* ecv = ecvB + (size_t)gph * E;
    const float* H = HB + (size_t)gph * N * 64;
    float* out = outB + (size_t)gph * N * 64;
    __shared__ short Zh[16 * 72], Zl[16 * 72];
    int tid = threadIdx.x, wave = tid >> 6, lane = tid & 63;
    int g = lane >> 4, f4 = (lane & 15) * 4;
    int rbase = blockIdx.x * 16;
    float4 b = *(const float4*)(bias + f4);
#pragma unroll
    for (int rr = 0; rr < 4; rr++) {
        int lr = wave * 4 + rr;
        int row = rbase + lr;
        if (row < N) {
            float ax, ay, az, aw;
            spmm_row4(offs, ecv, H, row, g, f4, ax, ay, az, aw);
            if (g == 0) {
                float zx = selu_f(ax + b.x);
                float zy = selu_f(ay + b.y);
                float zz = selu_f(az + b.z);
                float zw = selu_f(aw + b.w);
                short4v h, l;
                h.x = f2bf(zx); l.x = f2bf(zx - bf2f(h.x));
                h.y = f2bf(zy); l.y = f2bf(zy - bf2f(h.y));
                h.z = f2bf(zz); l.z = f2bf(zz - bf2f(h.z));
                h.w = f2bf(zw); l.w = f2bf(zw - bf2f(h.w));
                *(short4v*)(&Zh[lr * 72 + f4]) = h;
                *(short4v*)(&Zl[lr * 72 + f4]) = l;
            }
        } else if (g == 0) {
            short4v zv = {0, 0, 0, 0};
            *(short4v*)(&Zh[lr * 72 + f4]) = zv;
            *(short4v*)(&Zl[lr * 72 + f4]) = zv;
        }
    }
    __syncthreads();
    int m_ = lane & 15, q = lane >> 4;
    int ar = m_ * 72;
    short8 ah0 = *(const short8*)(&Zh[ar + q * 8]);
    short8 ah1 = *(const short8*)(&Zh[ar + 32 + q * 8]);
    short8 al0 = *(const short8*)(&Zl[ar + q * 8]);
    short8 al1 = *(const short8*)(&Zl[ar + 32 + q * 8]);
    const short* bhp = w2th + (size_t)(wave * 16 + m_) * 64;
    const short* blp = w2tl + (size_t)(wave * 16 + m_) * 64;
    short8 bh0 = *(const short8*)(bhp + q * 8);
    short8 bh1 = *(const short8*)(bhp + 32 + q * 8);
    short8 bl0 = *(const short8*)(blp + q * 8);
    short8 bl1 = *(const short8*)(blp + 32 + q * 8);
    f32x4 acc = {0.f, 0.f, 0.f, 0.f};
    acc = __builtin_amdgcn_mfma_f32_16x16x32_bf16(ah0, bh0, acc, 0, 0, 0);
    acc = __builtin_amdgcn_mfma_f32_16x16x32_bf16(al0, bh0, acc, 0, 0, 0);
    acc = __builtin_amdgcn_mfma_f32_16x16x32_bf16(ah0, bl0, acc, 0, 0, 0);
    acc = __builtin_amdgcn_mfma_f32_16x16x32_bf16(ah1, bh1, acc, 0, 0, 0);
    acc = __builtin_amdgcn_mfma_f32_16x16x32_bf16(al1, bh1, acc, 0, 0, 0);
    acc = __builtin_amdgcn_mfma_f32_16x16x32_bf16(ah1, bl1, acc, 0, 0, 0);
#pragma unroll
    for (int r = 0; r < 4; r++) {
        int grow = rbase + q * 4 + r;
        if (grow < N) out[(size_t)grow * 64 + wave * 16 + m_] = acc[r];
    }
}

// ---------------- spmm_norm: Z2 = A@Y + b2, row-L2-normalize ----------------
__global__ __launch_bounds__(256) void spmm_norm(const int* __restrict__ offsB,
                                                 const int2* __restrict__ ecvB,
                                                 const float* __restrict__ HB,
                                                 const float* __restrict__ bias,
                                                 float* __restrict__ outB,
                                                 int N, int E) {
    int gph = blockIdx.y;
    const int* offs = offsB + (size_t)gph * (N + 1);
    const int2* ecv = ecvB + (size_t)gph * E;
    const float* H = HB + (size_t)gph * N * 64;
    float* out = outB + (size_t)gph * N * 64;
    int row = blockIdx.x * 4 + (threadIdx.x >> 6);
    if (row >= N) return;
    int lane = threadIdx.x & 63;
    int g = lane >> 4, f4 = (lane & 15) * 4;
    float ax, ay, az, aw;
    spmm_row4(offs, ecv, H, row, g, f4, ax, ay, az, aw);
    float4 b = *(const float4*)(bias + f4);
    float zx = ax + b.x, zy = ay + b.y, zz = az + b.z, zw = aw + b.w;
    float s2 = zx * zx + zy * zy + zz * zz + zw * zw;
#pragma unroll
    for (int d = 1; d <= 8; d <<= 1) s2 += __shfl_xor(s2, d, 64);
    float inv = 1.0f / fmaxf(sqrtf(s2), 1e-12f);
    if (g == 0) {
        float4 o;
        o.x = zx * inv; o.y = zy * inv; o.z = zz * inv; o.w = zw * inv;
        *(float4*)(out + (size_t)row * 64 + f4) = o;
    }
}

extern "C" void kernel_launch(void* const* d_in, const int* in_sizes, int n_in,
                              void* d_out, int out_size, void* d_ws, size_t ws_size,
                              hipStream_t stream) {
    const int IN_DIM = 256, HID = 64;
    const int N = in_sizes[0] / IN_DIM;   // 100000
    const int E = in_sizes[2];            // 1200000

    const float* X1 = (const float*)d_in[0];
    const float* X2 = (const float*)d_in[1];
    const int*   r0 = (const int*)d_in[2];
    const int*   c0 = (const int*)d_in[3];
    const float* v0 = (const float*)d_in[4];
    const int*   r1 = (const int*)d_in[5];
    const int*   c1 = (const int*)d_in[6];
    const float* v1 = (const float*)d_in[7];
    const float* W1 = (const float*)d_in[8];
    const float* b1 = (const float*)d_in[9];
    const float* W2 = (const float*)d_in[10];
    const float* b2 = (const float*)d_in[11];
    float* out = (float*)d_out;

    const int NB  = (N + RPB - 1) / RPB;      // 196
    const int nbA = (E + EPB - 1) / EPB;      // 293
    const int M   = NB * nbA;
    const int nbScanM = (M + 1023) / 1024;    // 57
    const int nbGemm = (N + 63) / 64;         // 1563
    const int nbRow  = (N + 3) / 4;           // 25000
    const int nbFuse = (N + 15) / 16;         // 6250

    // gemm tile split across the three fat dispatches (~10/45/45%)
    const int T1 = nbGemm / 10;               // 156
    const int T2 = (nbGemm * 45) / 100;       // 703
    const int T3 = nbGemm - T1 - T2;          // 704

    auto align16 = [](char* p) { return (char*)(((uintptr_t)p + 15) & ~(uintptr_t)15); };
    char* w = (char*)d_ws;
    float* bufA   = (float*)w; w += (size_t)2 * N * HID * sizeof(float);
    float* bufB   = (float*)w; w += (size_t)2 * N * HID * sizeof(float);
    w = align16(w);
    int2*  ecv    = (int2*)w;  w += (size_t)2 * E * sizeof(int2);
    w = align16(w);
    int2*  ecvA   = (int2*)w;  w += (size_t)2 * E * sizeof(int2);   // no longer aliased: gemm runs concurrently with sort
    w = align16(w);
    int*   cntT   = (int*)w;   w += (size_t)2 * M * sizeof(int);
    w = align16(w);
    int*   csOffs = (int*)w;   w += (size_t)2 * (M + 1) * sizeof(int);
    w = align16(w);
    int*   offs   = (int*)w;   w += (size_t)2 * (N + 1) * sizeof(int);
    w = align16(w);
    int*   partials = (int*)w; w += 2 * 512 * sizeof(int);
    w = align16(w);
    short* w1th = (short*)w;   w += (size_t)64 * IN_DIM * sizeof(short);
    short* w1tl = (short*)w;   w += (size_t)64 * IN_DIM * sizeof(short);
    short* w2th = (short*)w;   w += (size_t)64 * HID * sizeof(short);
    short* w2tl = (short*)w;   w += (size_t)64 * HID * sizeof(short);
    float* bufA1 = bufA + (size_t)N * HID;

    // weight prep (tiny; must precede fat1's gemm slice)
    prep_w2<<<(IN_DIM * 64 + HID * 64 + 255) / 256, 256, 0, stream>>>(
        W1, w1th, w1tl, W2, w2th, w2tl);

    // fat1: hist (both graphs) + gemm tiles [0, T1)
    fat_hist_gemm<<<2 * nbA + 2 * T1, 256, 0, stream>>>(
        r0, r1, cntT, E, nbA, NB, M,
        X1, X2, w1th, w1tl, bufA, bufA1, N, 0, T1);
    scan_a<<<dim3(nbScanM, 2), 256, 0, stream>>>(cntT, csOffs, partials, M);
    scan_b<<<dim3(1, 2), 128, 0, stream>>>(partials, nbScanM);
    scan_c<<<dim3(nbScanM, 2), 256, 0, stream>>>(csOffs, partials, M, E);
    // fat2: coarse scatter + gemm tiles [T1, T1+T2)
    fat_scatter_gemm<<<2 * nbA + 2 * T2, 256, 0, stream>>>(
        r0, r1, c0, c1, v0, v1, csOffs, ecvA, E, nbA, NB, M,
        X1, X2, w1th, w1tl, bufA, bufA1, N, T1, T2);
    // fat3: fine sort + gemm tiles [T1+T2, nbGemm)
    fat_sort_gemm<<<2 * NB + 2 * T3, 256, 0, stream>>>(
        csOffs, ecvA, ecv, offs, nbA, N, E, M, NB,
        X1, X2, w1th, w1tl, bufA, bufA1, N, T1 + T2, T3);

    // fused: Z1 = selu(A@H + b1); Y = Z1@W2 -> bufB
    spmm_selu_w2<<<dim3(nbFuse, 2), 256, 0, stream>>>(offs, ecv, bufA, b1,
                                                      w2th, w2tl, bufB, N, E);
    // layer 2 aggregation + bias + L2 normalize -> out
    spmm_norm<<<dim3(nbRow, 2), 256, 0, stream>>>(offs, ecv, bufB, b2, out, N, E);
}